// Round 18
// baseline (140.214 us; speedup 1.0000x reference)
//
#include <hip/hip_runtime.h>
#include <math.h>

using f32x4  = __attribute__((ext_vector_type(4))) float;
using bf16x8 = __attribute__((ext_vector_type(8))) short;

#define GLOAD_LDS16(gp, lp)                                            \
  __builtin_amdgcn_global_load_lds(                                    \
      (const __attribute__((address_space(1))) void*)(gp),             \
      (__attribute__((address_space(3))) void*)(lp), 16, 0, 0)

namespace {
constexpr int N_ROWS = 4096;
constexpr int D      = 1024;
constexpr int CUT0   = 2000, CUT1 = 10000, VTOT = 50257;
constexpr int HM   = 2002;                 // head cols (2000 + 2 cluster)
constexpr int HMP  = 2048;                 // padded head cols (pad = 46)
constexpr int T0M  = 8000,              T0MP = 8000;    // pad 0
constexpr int T1M  = VTOT - CUT1;                        // 40257
constexpr int T1MP = 40272;                              // pad 15
constexpr float LOG2E = 1.4426950408889634f;
constexpr int POS_NONE = 0x7FFFFFFF;
constexpr int POS_C1   = 1 << 30;
// tails: row-split waves, B shared via LDS double-buffer
constexpr int SL1 = 96, SL0 = 64;
constexpr int RPB1 = 128, RPB0 = 64;       // rows per block (32 / 16 per wave)
constexpr int G_T1 = (N_ROWS / RPB1) * SL1;       // 3072 blocks (worst case)
constexpr int G_T0 = (N_ROWS / RPB0) * SL0;       // 4096 blocks (worst case)
// fused-convert region boundaries (elements): hidden first, then weights
constexpr long long BH = (long long)N_ROWS * D;
constexpr long long B0 = (long long)HMP * D;
constexpr long long B1 = B0 + (long long)T0MP * 256;
constexpr long long B2 = B1 + (long long)T1MP * 64;
constexpr long long B3 = B2 + (long long)256 * D;
constexpr long long B4 = B3 + (long long)64 * D;
constexpr long long TOT = BH + B4;
constexpr int NCONV = (int)((TOT / 8 + 255) / 256);   // convert blocks
}

__device__ __forceinline__ unsigned short f2bf(float x) {
  unsigned u = __builtin_bit_cast(unsigned, x);
  u += 0x7FFFu + ((u >> 16) & 1u);
  return (unsigned short)(u >> 16);
}
__device__ __forceinline__ float bf2f(unsigned short b) {
  unsigned u = ((unsigned)b) << 16;
  return __builtin_bit_cast(float, u);
}
__device__ __forceinline__ bf16x8 pack8(float4 f0, float4 f1, float sc) {
  bf16x8 o;
  o[0] = f2bf(f0.x * sc); o[1] = f2bf(f0.y * sc);
  o[2] = f2bf(f0.z * sc); o[3] = f2bf(f0.w * sc);
  o[4] = f2bf(f1.x * sc); o[5] = f2bf(f1.y * sc);
  o[6] = f2bf(f1.z * sc); o[7] = f2bf(f1.w * sc);
  return o;
}

// ---- prep: fused converts (hidden swizzled-bf16 + all weights) + scan ----

__global__ __launch_bounds__(256) void prep_k(
    const float* __restrict__ hidden, const float* __restrict__ hw,
    const float* __restrict__ t0, const float* __restrict__ t1,
    const float* __restrict__ p0, const float* __restrict__ p1,
    unsigned short* __restrict__ hbf, unsigned short* __restrict__ dhw,
    unsigned short* __restrict__ dt0, unsigned short* __restrict__ dt1,
    unsigned short* __restrict__ dp0, unsigned short* __restrict__ dp1,
    const int* __restrict__ tgt, int* __restrict__ cnt,
    int* __restrict__ l0, int* __restrict__ l1, int* __restrict__ pos) {
  if (blockIdx.x == NCONV) {              // last block: compaction scan
    __shared__ int s0[256], s1[256];
    int tid = threadIdx.x;
    int c0 = 0, c1 = 0;
#pragma unroll
    for (int j = 0; j < 16; ++j) {
      int v = tgt[tid * 16 + j];
      c0 += (v >= CUT0 && v < CUT1);
      c1 += (v >= CUT1);
    }
    s0[tid] = c0; s1[tid] = c1;
    __syncthreads();
    for (int off = 1; off < 256; off <<= 1) {
      int a0 = (tid >= off) ? s0[tid - off] : 0;
      int a1 = (tid >= off) ? s1[tid - off] : 0;
      __syncthreads();
      s0[tid] += a0; s1[tid] += a1;
      __syncthreads();
    }
    int b0 = s0[tid] - c0, b1 = s1[tid] - c1;
#pragma unroll
    for (int j = 0; j < 16; ++j) {
      int row = tid * 16 + j;
      int v = tgt[row];
      if (v >= CUT0 && v < CUT1)      { l0[b0] = row; pos[row] = b0; ++b0; }
      else if (v >= CUT1)             { l1[b1] = row; pos[row] = b1 | POS_C1; ++b1; }
      else                            { pos[row] = POS_NONE; }
    }
    if (tid == 255) { cnt[0] = s0[255]; cnt[1] = s1[255]; }
    return;
  }
  long long i = ((long long)blockIdx.x * 256 + threadIdx.x) * 8;
  if (i >= TOT) return;
  if (i < BH) {                           // hidden -> swizzled bf16 tiles
    int c = (int)(i >> 3);
    int row = c >> 7, k8 = c & 127;
    const float* hp = hidden + (size_t)row * D + k8 * 8;
    float4 f0 = *(const float4*)hp, f1 = *(const float4*)(hp + 4);
    bf16x8 o = pack8(f0, f1, 1.f);
    size_t tb = (size_t)(row >> 6) * 131072;
    int boff = (((row & 63) * 2048 + k8 * 16) ^ ((row & 7) << 4));
    *(bf16x8*)((char*)hbf + tb + boff) = o;
    return;
  }
  long long j = i - BH;
  const float* src; unsigned short* dst; long long off, nsrc;
  float scale = LOG2E;
  if (j < B0)      { src = hw; dst = dhw; off = j;      nsrc = (long long)HM * D; }
  else if (j < B1) { src = t0; dst = dt0; off = j - B0; nsrc = (long long)T0M * 256; }
  else if (j < B2) { src = t1; dst = dt1; off = j - B1; nsrc = (long long)T1M * 64; }
  else if (j < B3) { src = p0; dst = dp0; off = j - B2; nsrc = (long long)256 * D; scale = 1.f; }
  else             { src = p1; dst = dp1; off = j - B3; nsrc = (long long)64 * D;  scale = 1.f; }
  bf16x8 o;
  if (off < nsrc) {   // region sizes and nsrc are multiples of 8
    float4 f0 = *(const float4*)(src + off), f1 = *(const float4*)(src + off + 4);
    o = pack8(f0, f1, scale);
  } else {
    o = bf16x8{0, 0, 0, 0, 0, 0, 0, 0};
  }
  *(bf16x8*)(dst + off) = o;
}

// ------ headz: 32-row A tile (64KB LDS -> 2 blocks/CU), fused z-proj ------

__global__ __launch_bounds__(512) void headz_k(const unsigned short* __restrict__ hbf,
    const unsigned short* __restrict__ hwbf, const unsigned short* __restrict__ p0bf,
    const unsigned short* __restrict__ p1bf, const int* __restrict__ posc,
    unsigned short* __restrict__ z0, unsigned short* __restrict__ z1,
    float* __restrict__ hs_part) {
  __shared__ char Ab[32 * 2048];            // 64 KB swizzled bf16 (pre-baked)
  __shared__ float red[8][32];
  int rb = blockIdx.x >> 2, slice = blockIdx.x & 3;   // 128 rowblocks x 4 slices
  int tid = threadIdx.x;

  // stage 64KB half-image via global_load_lds (linear, wave-uniform+lane*16)
  const char* srcb = (const char*)hbf + (size_t)rb * 65536;
#pragma unroll
  for (int j = 0; j < 8; ++j) {
    int c = j * 512 + tid;
    GLOAD_LDS16(srcb + (size_t)c * 16, Ab + c * 16);
  }
  __syncthreads();

  int w = tid >> 6, l = tid & 63, lr = l & 15, kg = l >> 4;
  int tg0 = (slice * 8 + w) * 4;            // this wave's 4 head col-tiles
  int zt = slice * 8 + w;                   // this wave's z col-tile (if <20)
  bool hasz = zt < 20;
  const unsigned short* zb = hasz
      ? (zt < 16 ? p0bf + (size_t)(zt * 16 + lr) * D
                 : p1bf + (size_t)((zt - 16) * 16 + lr) * D)
      : p0bf;
  f32x4 zero4 = {0.f, 0.f, 0.f, 0.f};
  f32x4 acc[2][4];                          // [rowgroup][tile]
  f32x4 zac[2];
#pragma unroll
  for (int rg = 0; rg < 2; ++rg) {
    zac[rg] = zero4;
#pragma unroll
    for (int t = 0; t < 4; ++t) acc[rg][t] = zero4;
  }

#pragma unroll 4
  for (int kc = 0; kc < 32; ++kc) {
    bf16x8 af[2], bf[4];
#pragma unroll
    for (int rg = 0; rg < 2; ++rg) {
      int addr = ((rg * 16 + lr) * 2048 + kc * 64 + kg * 16) ^ ((lr & 7) << 4);
      af[rg] = *(const bf16x8*)(Ab + addr);
    }
#pragma unroll
    for (int t = 0; t < 4; ++t)
      bf[t] = *(const bf16x8*)(hwbf + (size_t)((tg0 + t) * 16 + lr) * D + kc * 32 + kg * 8);
#pragma unroll
    for (int rg = 0; rg < 2; ++rg)
#pragma unroll
      for (int t = 0; t < 4; ++t)
        acc[rg][t] = __builtin_amdgcn_mfma_f32_16x16x32_bf16(af[rg], bf[t], acc[rg][t], 0, 0, 0);
    if (hasz) {                             // wave-uniform branch
      bf16x8 bz = *(const bf16x8*)(zb + kc * 32 + kg * 8);
#pragma unroll
      for (int rg = 0; rg < 2; ++rg)
        zac[rg] = __builtin_amdgcn_mfma_f32_16x16x32_bf16(af[rg], bz, zac[rg], 0, 0, 0);
    }
  }

  // head epilogue: sum exp2 over this wave's 64 cols
  float sv[2][4];
#pragma unroll
  for (int rg = 0; rg < 2; ++rg)
#pragma unroll
    for (int v = 0; v < 4; ++v) {
      float s = 0.f;
#pragma unroll
      for (int t = 0; t < 4; ++t) s += __builtin_amdgcn_exp2f(acc[rg][t][v]);
      sv[rg][v] = s;
    }
#pragma unroll
  for (int off = 1; off < 16; off <<= 1)
#pragma unroll
    for (int rg = 0; rg < 2; ++rg)
#pragma unroll
      for (int v = 0; v < 4; ++v) sv[rg][v] += __shfl_xor(sv[rg][v], off);
  if (lr == 0)
#pragma unroll
    for (int rg = 0; rg < 2; ++rg)
#pragma unroll
      for (int v = 0; v < 4; ++v) red[w][rg * 16 + kg * 4 + v] = sv[rg][v];

  // z epilogue: write compacted z rows (cluster-matched only)
  if (hasz) {
#pragma unroll
    for (int rg = 0; rg < 2; ++rg)
#pragma unroll
      for (int v = 0; v < 4; ++v) {
        int grow = rb * 32 + rg * 16 + kg * 4 + v;
        int pcv = posc[grow];
        if (zt < 16) {
          if (pcv < POS_C1)
            z0[(size_t)pcv * 256 + zt * 16 + lr] = f2bf(zac[rg][v]);
        } else {
          if (pcv != POS_NONE && pcv >= POS_C1)
            z1[(size_t)(pcv & (POS_C1 - 1)) * 64 + (zt - 16) * 16 + lr] = f2bf(zac[rg][v]);
        }
      }
  }
  __syncthreads();
  if (tid < 32) {
    float s = 0.f;
#pragma unroll
    for (int ww = 0; ww < 8; ++ww) s += red[ww][tid];
    hs_part[slice * N_ROWS + rb * 32 + tid] = s;
  }
}

// --- tails: row-split waves, B staged once per block in LDS (dbuf) --------

__device__ __forceinline__ void tail1_body(int bid, const unsigned short* __restrict__ z,
    const unsigned short* __restrict__ twbf, const int* __restrict__ list,
    const int* __restrict__ cntp, float* __restrict__ ts_part,
    char* __restrict__ Bl) {
  constexpr int MT = T1MP / 16;             // 2517
  constexpr int ST = (MT + SL1 - 1) / SL1;  // 27
  int n = *cntp;
  int rowblock = bid / SL1, slice = bid % SL1;
  int rowbase = rowblock * RPB1;
  if (rowbase >= n) return;                 // block-uniform
  int t0 = slice * ST, t1e = min(t0 + ST, MT);
  if (t0 >= t1e) return;                    // block-uniform
  int tid = threadIdx.x, w = tid >> 6, l = tid & 63, lr = l & 15, kg = l >> 4;

  bf16x8 a[2][2];
#pragma unroll
  for (int rg = 0; rg < 2; ++rg) {
    int idx = min(rowbase + w * 32 + rg * 16 + lr, n - 1);
    const unsigned short* zp = z + (size_t)idx * 64 + kg * 8;
    a[rg][0] = *(const bf16x8*)(zp);
    a[rg][1] = *(const bf16x8*)(zp + 32);
  }

  int sb = tid * 16;
  int stile = sb >> 11, scol = (sb >> 7) & 15;
  int sbyte = (sb & 127) ^ ((scol & 7) << 4);
  const char* tb = (const char*)twbf;
  int mtm1 = MT - 1;
  auto stage = [&](int gt, int buf) {
    int tA = min(gt + stile, mtm1);
    GLOAD_LDS16(tb + (size_t)tA * 2048 + scol * 128 + sbyte, Bl + buf * 4096 + sb);
  };

  int NG = (t1e - t0 + 1) >> 1;
  stage(t0, 0);
  __syncthreads();

  float s[2][4] = {};
  f32x4 zero4 = {0.f, 0.f, 0.f, 0.f};
  int rd0 = (lr * 128 + kg * 16) ^ ((lr & 7) << 4);
  int cur = 0;
  for (int g = 0; g < NG; ++g) {
    int gt = t0 + g * 2;
    if (g + 1 < NG) stage(gt + 2, cur ^ 1);
#pragma unroll
    for (int t = 0; t < 2; ++t) {
      if (gt + t < t1e) {                   // block-uniform guard
        const char* bb = Bl + cur * 4096 + t * 2048;
        bf16x8 b0 = *(const bf16x8*)(bb + rd0);
        bf16x8 b1 = *(const bf16x8*)(bb + (rd0 ^ 64));
        f32x4 acc0 = __builtin_amdgcn_mfma_f32_16x16x32_bf16(a[0][0], b0, zero4, 0, 0, 0);
        f32x4 acc1 = __builtin_amdgcn_mfma_f32_16x16x32_bf16(a[1][0], b0, zero4, 0, 0, 0);
        acc0 = __builtin_amdgcn_mfma_f32_16x16x32_bf16(a[0][1], b1, acc0, 0, 0, 0);
        acc1 = __builtin_amdgcn_mfma_f32_16x16x32_bf16(a[1][1], b1, acc1, 0, 0, 0);
#pragma unroll
        for (int v = 0; v < 4; ++v) {
          s[0][v] += __builtin_amdgcn_exp2f(acc0[v]);
          s[1][v] += __builtin_amdgcn_exp2f(acc1[v]);
        }
      }
    }
    __syncthreads();
    cur ^= 1;
  }

#pragma unroll
  for (int off = 1; off < 16; off <<= 1)
#pragma unroll
    for (int rg = 0; rg < 2; ++rg)
#pragma unroll
      for (int v = 0; v < 4; ++v) s[rg][v] += __shfl_xor(s[rg][v], off);
  if (lr == 0) {
#pragma unroll
    for (int rg = 0; rg < 2; ++rg)
#pragma unroll
      for (int v = 0; v < 4; ++v) {
        int idx = rowbase + w * 32 + rg * 16 + kg * 4 + v;
        if (idx < n)
          ts_part[(size_t)slice * N_ROWS + list[idx]] = s[rg][v];
      }
  }
}

__device__ __forceinline__ void tail0_body(int bid, const unsigned short* __restrict__ z,
    const unsigned short* __restrict__ twbf, const int* __restrict__ list,
    const int* __restrict__ cntp, float* __restrict__ ts_part,
    char* __restrict__ Bl) {
  constexpr int MT = T0MP / 16;             // 500
  constexpr int ST = (MT + SL0 - 1) / SL0;  // 8
  int n = *cntp;
  int rowblock = bid / SL0, slice = bid % SL0;
  int rowbase = rowblock * RPB0;
  if (rowbase >= n) return;
  int t0 = slice * ST, t1e = min(t0 + ST, MT);
  if (t0 >= t1e) return;
  int tid = threadIdx.x, w = tid >> 6, l = tid & 63, lr = l & 15, kg = l >> 4;

  bf16x8 a[8];
  {
    int idx = min(rowbase + w * 16 + lr, n - 1);
    const unsigned short* zp = z + (size_t)idx * 256 + kg * 8;
#pragma unroll
    for (int kc = 0; kc < 8; ++kc) a[kc] = *(const bf16x8*)(zp + kc * 32);
  }

  int sb0 = tid * 16, sb1 = sb0 + 4096;
  int c0s = sb0 >> 9, b0s = (sb0 & 511) ^ ((c0s & 7) << 4);
  int c1s = sb1 >> 9, b1s = (sb1 & 511) ^ ((c1s & 7) << 4);
  const char* tb = (const char*)twbf;
  auto stage = [&](int gt, int buf) {
    GLOAD_LDS16(tb + (size_t)gt * 8192 + c0s * 512 + b0s, Bl + buf * 8192 + sb0);
    GLOAD_LDS16(tb + (size_t)gt * 8192 + c1s * 512 + b1s, Bl + buf * 8192 + sb1);
  };

  int NG = t1e - t0;
  stage(t0, 0);
  __syncthreads();

  float s[4] = {};
  f32x4 zero4 = {0.f, 0.f, 0.f, 0.f};
  int swz = (lr & 7) << 4;
  int rdb = lr * 512 + kg * 16;
  int cur = 0;
  for (int g = 0; g < NG; ++g) {
    if (g + 1 < NG) stage(t0 + g + 1, cur ^ 1);
    const char* bb = Bl + cur * 8192;
    f32x4 acc = zero4;
#pragma unroll
    for (int kc = 0; kc < 8; ++kc) {
      bf16x8 b = *(const bf16x8*)(bb + ((rdb + kc * 64) ^ swz));
      acc = __builtin_amdgcn_mfma_f32_16x16x32_bf16(a[kc], b, acc, 0, 0, 0);
    }
#pragma unroll
    for (int v = 0; v < 4; ++v) s[v] += __builtin_amdgcn_exp2f(acc[v]);
    __syncthreads();
    cur ^= 1;
  }

#pragma unroll
  for (int off = 1; off < 16; off <<= 1)
#pragma unroll
    for (int v = 0; v < 4; ++v) s[v] += __shfl_xor(s[v], off);
  if (lr == 0) {
#pragma unroll
    for (int v = 0; v < 4; ++v) {
      int idx = rowbase + w * 16 + kg * 4 + v;
      if (idx < n)
        ts_part[(size_t)slice * N_ROWS + list[idx]] = s[v];
    }
  }
}

__global__ __launch_bounds__(256, 8) void tf_k(
    const unsigned short* __restrict__ z0, const unsigned short* __restrict__ t0bf,
    const unsigned short* __restrict__ z1, const unsigned short* __restrict__ t1bf,
    const int* __restrict__ l0, const int* __restrict__ l1,
    const int* __restrict__ cnt, float* __restrict__ ts0_part,
    float* __restrict__ ts1_part) {
  __shared__ char Bl[16384];
  int b = blockIdx.x;
  if (b < G_T1)
    tail1_body(b, z1, t1bf, l1, cnt + 1, ts1_part, Bl);
  else
    tail0_body(b - G_T1, z0, t0bf, l0, cnt + 0, ts0_part, Bl);
}

// ---------------- finalize ----------------

__global__ __launch_bounds__(256) void finalize_k(const float* __restrict__ hidden,
    const int* __restrict__ tgt, const float* __restrict__ head_w,
    const float* __restrict__ tail0, const float* __restrict__ tail1,
    const unsigned short* __restrict__ z0, const unsigned short* __restrict__ z1,
    const int* __restrict__ pos, const float* __restrict__ hs_part,
    const float* __restrict__ ts0_part, const float* __restrict__ ts1_part,
    float* __restrict__ out) {
  int w = threadIdx.x >> 6, l = threadIdx.x & 63;
  int row = blockIdx.x * 4 + w;
  int t = tgt[row];
  int jt = t < 0 ? 0 : (t < CUT0 ? t : (t < CUT1 ? CUT0 : CUT0 + 1));
  const float4* h4 = (const float4*)(hidden + (size_t)row * D);
  const float4* w4 = (const float4*)(head_w + (size_t)jt * D);
  float acc = 0.f;
#pragma unroll
  for (int j = 0; j < 4; ++j) {
    float4 a = h4[l + 64 * j], b = w4[l + 64 * j];
    acc += a.x * b.x + a.y * b.y + a.z * b.z + a.w * b.w;
  }
  float hp = (l < 4) ? hs_part[l * N_ROWS + row] : 0.f;
#pragma unroll
  for (int off = 32; off; off >>= 1) {
    acc += __shfl_xor(acc, off);
    hp  += __shfl_xor(hp, off);
  }
  float val = acc - __logf(hp - 46.f);      // subtract 46 zero-pad cols
  if (t >= CUT0) {
    int p = pos[row] & (POS_C1 - 1);
    float ta = 0.f, tp = 0.f;
    if (t < CUT1) {
      const unsigned short* zr = z0 + (size_t)p * 256;
      const float* tw = tail0 + (size_t)(t - CUT0) * 256;
#pragma unroll
      for (int j = 0; j < 4; ++j) ta += bf2f(zr[l + 64 * j]) * tw[l + 64 * j];
      tp = ts0_part[(size_t)l * N_ROWS + row];            // SL0 = 64 slices
    } else {
      const unsigned short* zr = z1 + (size_t)p * 64;
      const float* tw = tail1 + (size_t)(t - CUT1) * 64;
      ta = bf2f(zr[l]) * tw[l];
      tp = ts1_part[(size_t)l * N_ROWS + row];            // slices 0..63
      if (l < SL1 - 64) tp += ts1_part[(size_t)(64 + l) * N_ROWS + row];
    }
#pragma unroll
    for (int off = 32; off; off >>= 1) {
      ta += __shfl_xor(ta, off);
      tp += __shfl_xor(tp, off);
    }
    float lt = tp - ((t >= CUT1) ? 15.f : 0.f);  // subtract zero-pad cols
    val += ta - __logf(lt);
  }
  if (l == 0) out[row] = (t < 0) ? 0.f : val;
}

// ---------------- loss ----------------

__global__ __launch_bounds__(256) void loss_k(const float* __restrict__ out,
                                              const int* __restrict__ target,
                                              float* __restrict__ loss) {
  __shared__ float ssum[256];
  __shared__ int scnt[256];
  float s = 0.f; int c = 0;
  for (int i = threadIdx.x; i < N_ROWS; i += 256) {
    s += out[i];
    if (target[i] >= 0) c++;
  }
  ssum[threadIdx.x] = s; scnt[threadIdx.x] = c;
  __syncthreads();
  for (int off = 128; off; off >>= 1) {
    if (threadIdx.x < off) {
      ssum[threadIdx.x] += ssum[threadIdx.x + off];
      scnt[threadIdx.x] += scnt[threadIdx.x + off];
    }
    __syncthreads();
  }
  if (threadIdx.x == 0) {
    int nv = scnt[0];
    loss[0] = (nv > 0) ? (-ssum[0] / (float)nv) : 0.f;
  }
}

// ---------------- launch ----------------

extern "C" void kernel_launch(void* const* d_in, const int* in_sizes, int n_in,
                              void* d_out, int out_size, void* d_ws, size_t ws_size,
                              hipStream_t stream) {
  const float* hidden = (const float*)d_in[0];
  const int*   target = (const int*)d_in[1];
  const float* head_w = (const float*)d_in[2];
  const float* proj0  = (const float*)d_in[3];
  const float* tail0  = (const float*)d_in[4];
  const float* proj1  = (const float*)d_in[5];
  const float* tail1  = (const float*)d_in[6];
  float* out = (float*)d_out;

  char* wp = (char*)d_ws;
  auto alloc = [&](size_t bytes) {
    char* p = wp;
    wp += (bytes + 255) & ~(size_t)255;
    return p;
  };
  int* cnt   = (int*)alloc(8);
  int* list0 = (int*)alloc(N_ROWS * 4);
  int* list1 = (int*)alloc(N_ROWS * 4);
  int* pos   = (int*)alloc(N_ROWS * 4);
  unsigned short* hbf  = (unsigned short*)alloc((size_t)N_ROWS * D * 2);
  unsigned short* hwbf = (unsigned short*)alloc((size_t)HMP * D * 2);
  unsigned short* t0bf = (unsigned short*)alloc((size_t)T0MP * 256 * 2);
  unsigned short* t1bf = (unsigned short*)alloc((size_t)T1MP * 64 * 2);
  unsigned short* p0bf = (unsigned short*)alloc((size_t)256 * D * 2);
  unsigned short* p1bf = (unsigned short*)alloc((size_t)64 * D * 2);
  unsigned short* z0   = (unsigned short*)alloc((size_t)N_ROWS * 256 * 2);
  unsigned short* z1   = (unsigned short*)alloc((size_t)N_ROWS * 64 * 2);
  float* hs_part  = (float*)alloc((size_t)4 * N_ROWS * 4);
  float* ts0_part = (float*)alloc((size_t)SL0 * N_ROWS * 4);
  float* ts1_part = (float*)alloc((size_t)SL1 * N_ROWS * 4);

  prep_k<<<NCONV + 1, 256, 0, stream>>>(hidden, head_w, tail0, tail1, proj0, proj1,
                                        hbf, hwbf, t0bf, t1bf, p0bf, p1bf,
                                        target, cnt, list0, list1, pos);
  headz_k<<<(N_ROWS / 32) * 4, 512, 0, stream>>>(hbf, hwbf, p0bf, p1bf, pos,
                                                 z0, z1, hs_part);
  tf_k<<<G_T1 + G_T0, 256, 0, stream>>>(z0, t0bf, z1, t1bf, list0, list1, cnt,
                                        ts0_part, ts1_part);
  finalize_k<<<N_ROWS / 4, 256, 0, stream>>>(hidden, target, head_w, tail0, tail1,
                                             z0, z1, pos, hs_part, ts0_part, ts1_part, out);
  loss_k<<<1, 256, 0, stream>>>(out, target, out + N_ROWS);
}

// Round 20
// 123.958 us; speedup vs baseline: 1.1311x; 1.1311x over previous
//
#include <hip/hip_runtime.h>
#include <math.h>

using f32x4  = __attribute__((ext_vector_type(4))) float;
using bf16x8 = __attribute__((ext_vector_type(8))) short;

#define GLOAD_LDS16(gp, lp)                                            \
  __builtin_amdgcn_global_load_lds(                                    \
      (const __attribute__((address_space(1))) void*)(gp),             \
      (__attribute__((address_space(3))) void*)(lp), 16, 0, 0)

namespace {
constexpr int N_ROWS = 4096;
constexpr int D      = 1024;
constexpr int CUT0   = 2000, CUT1 = 10000, VTOT = 50257;
constexpr int HM   = 2002;                 // head cols (2000 + 2 cluster)
constexpr int HMP  = 2048;                 // padded head cols (pad = 46)
constexpr int T0M  = 8000,              T0MP = 8000;    // pad 0
constexpr int T1M  = VTOT - CUT1;                        // 40257
constexpr int T1MP = 40272;                              // pad 15
constexpr float LOG2E = 1.4426950408889634f;
constexpr int POS_NONE = 0x7FFFFFFF;
constexpr int POS_C1   = 1 << 30;
// head: 64 rows x 128 cols per block, 16 col-slices
constexpr int HSL = 16;
constexpr int G_HK = (N_ROWS / 64) * HSL;         // 1024 blocks
// tails: row-split waves, B shared via LDS double-buffer
constexpr int SL1 = 96, SL0 = 64;
constexpr int RPB1 = 128, RPB0 = 64;       // rows per block (32 / 16 per wave)
constexpr int G_T1 = (N_ROWS / RPB1) * SL1;       // 3072 blocks (worst case)
constexpr int G_T0 = (N_ROWS / RPB0) * SL0;       // 4096 blocks (worst case)
// fused-convert region boundaries (elements): hidden first, then weights
constexpr long long BH = (long long)N_ROWS * D;
constexpr long long B0 = (long long)HMP * D;
constexpr long long B1 = B0 + (long long)T0MP * 256;
constexpr long long B2 = B1 + (long long)T1MP * 64;
constexpr long long B3 = B2 + (long long)256 * D;
constexpr long long B4 = B3 + (long long)64 * D;
constexpr long long TOT = BH + B4;
constexpr int NCONV = (int)((TOT / 8 + 255) / 256);   // convert blocks
}

__device__ __forceinline__ unsigned short f2bf(float x) {
  unsigned u = __builtin_bit_cast(unsigned, x);
  u += 0x7FFFu + ((u >> 16) & 1u);
  return (unsigned short)(u >> 16);
}
__device__ __forceinline__ float bf2f(unsigned short b) {
  unsigned u = ((unsigned)b) << 16;
  return __builtin_bit_cast(float, u);
}
__device__ __forceinline__ bf16x8 pack8(float4 f0, float4 f1, float sc) {
  bf16x8 o;
  o[0] = f2bf(f0.x * sc); o[1] = f2bf(f0.y * sc);
  o[2] = f2bf(f0.z * sc); o[3] = f2bf(f0.w * sc);
  o[4] = f2bf(f1.x * sc); o[5] = f2bf(f1.y * sc);
  o[6] = f2bf(f1.z * sc); o[7] = f2bf(f1.w * sc);
  return o;
}

// ---- prep: fused converts (hidden swizzled-bf16 + all weights) + scan ----

__global__ __launch_bounds__(256) void prep_k(
    const float* __restrict__ hidden, const float* __restrict__ hw,
    const float* __restrict__ t0, const float* __restrict__ t1,
    const float* __restrict__ p0, const float* __restrict__ p1,
    unsigned short* __restrict__ hbf, unsigned short* __restrict__ dhw,
    unsigned short* __restrict__ dt0, unsigned short* __restrict__ dt1,
    unsigned short* __restrict__ dp0, unsigned short* __restrict__ dp1,
    const int* __restrict__ tgt, int* __restrict__ cnt,
    int* __restrict__ l0, int* __restrict__ l1, int* __restrict__ pos) {
  if (blockIdx.x == NCONV) {              // last block: compaction scan
    __shared__ int s0[256], s1[256];
    int tid = threadIdx.x;
    int c0 = 0, c1 = 0;
#pragma unroll
    for (int j = 0; j < 16; ++j) {
      int v = tgt[tid * 16 + j];
      c0 += (v >= CUT0 && v < CUT1);
      c1 += (v >= CUT1);
    }
    s0[tid] = c0; s1[tid] = c1;
    __syncthreads();
    for (int off = 1; off < 256; off <<= 1) {
      int a0 = (tid >= off) ? s0[tid - off] : 0;
      int a1 = (tid >= off) ? s1[tid - off] : 0;
      __syncthreads();
      s0[tid] += a0; s1[tid] += a1;
      __syncthreads();
    }
    int b0 = s0[tid] - c0, b1 = s1[tid] - c1;
#pragma unroll
    for (int j = 0; j < 16; ++j) {
      int row = tid * 16 + j;
      int v = tgt[row];
      if (v >= CUT0 && v < CUT1)      { l0[b0] = row; pos[row] = b0; ++b0; }
      else if (v >= CUT1)             { l1[b1] = row; pos[row] = b1 | POS_C1; ++b1; }
      else                            { pos[row] = POS_NONE; }
    }
    if (tid == 255) { cnt[0] = s0[255]; cnt[1] = s1[255]; }
    return;
  }
  long long i = ((long long)blockIdx.x * 256 + threadIdx.x) * 8;
  if (i >= TOT) return;
  if (i < BH) {                           // hidden -> swizzled bf16 tiles
    int c = (int)(i >> 3);
    int row = c >> 7, k8 = c & 127;
    const float* hp = hidden + (size_t)row * D + k8 * 8;
    float4 f0 = *(const float4*)hp, f1 = *(const float4*)(hp + 4);
    bf16x8 o = pack8(f0, f1, 1.f);
    size_t tb = (size_t)(row >> 6) * 131072;
    int boff = (((row & 63) * 2048 + k8 * 16) ^ ((row & 7) << 4));
    *(bf16x8*)((char*)hbf + tb + boff) = o;
    return;
  }
  long long j = i - BH;
  const float* src; unsigned short* dst; long long off, nsrc;
  float scale = LOG2E;
  if (j < B0)      { src = hw; dst = dhw; off = j;      nsrc = (long long)HM * D; }
  else if (j < B1) { src = t0; dst = dt0; off = j - B0; nsrc = (long long)T0M * 256; }
  else if (j < B2) { src = t1; dst = dt1; off = j - B1; nsrc = (long long)T1M * 64; }
  else if (j < B3) { src = p0; dst = dp0; off = j - B2; nsrc = (long long)256 * D; scale = 1.f; }
  else             { src = p1; dst = dp1; off = j - B3; nsrc = (long long)64 * D;  scale = 1.f; }
  bf16x8 o;
  if (off < nsrc) {   // region sizes and nsrc are multiples of 8
    float4 f0 = *(const float4*)(src + off), f1 = *(const float4*)(src + off + 4);
    o = pack8(f0, f1, scale);
  } else {
    o = bf16x8{0, 0, 0, 0, 0, 0, 0, 0};
  }
  *(bf16x8*)(dst + off) = o;
}

// --- headk: head LSE + z-proj, tail-pattern: A in regs (K-chunked), B via
// --- global_load_lds dbuf LDS tiles, row-split waves. z: every wave does
// --- tile `slice` (z0) for its own rows; slices<4 also do z1 tile 16+slice.

__global__ __launch_bounds__(256) void headk_k(const unsigned short* __restrict__ hbf,
    const unsigned short* __restrict__ hwbf, const unsigned short* __restrict__ p0bf,
    const unsigned short* __restrict__ p1bf, const int* __restrict__ posc,
    unsigned short* __restrict__ z0, unsigned short* __restrict__ z1,
    float* __restrict__ hs_part) {
  __shared__ char Bl[16384];               // 2 x 8KB B tiles
  int rb = blockIdx.x >> 4, slice = blockIdx.x & 15;  // 64 rowblocks x 16 slices
  int tid = threadIdx.x, w = tid >> 6, l = tid & 63, lr = l & 15, kg = l >> 4;
  int row = rb * 64 + w * 16 + lr;         // this lane's A row (loads)

  // B staging constants (pre-swizzled source, linear LDS dest)
  int sb0 = tid * 16, sb1 = sb0 + 4096;
  int c0s = sb0 >> 9, b0s = (sb0 & 511) ^ ((c0s & 7) << 4);
  int c1s = sb1 >> 9, b1s = (sb1 & 511) ^ ((c1s & 7) << 4);
  const char* wb = (const char*)hwbf;
  int colbase = slice * 128;               // 128 cols (8 tiles) per block
  auto stage = [&](int p, int buf) {       // p = c*8 + t
    int c = p >> 3, t = p & 7;
    const char* src = wb + (size_t)(colbase + t * 16) * 2048 + c * 512;
    GLOAD_LDS16(src + (size_t)c0s * 2048 + b0s, Bl + buf * 8192 + sb0);
    GLOAD_LDS16(src + (size_t)c1s * 2048 + b1s, Bl + buf * 8192 + sb1);
  };

  // A image addressing (swizzled 64-row tiles)
  const char* ab = (const char*)hbf + (size_t)rb * 131072;
  int r63 = row & 63, rsw = (row & 7) << 4;

  // z operands: every wave does z0 tile `slice`; slices<4 also z1 tile 16+slice
  const unsigned short* zbA = p0bf + (size_t)(slice * 16 + lr) * D;
  bool hasB = slice < 4;
  const unsigned short* zbB = hasB ? p1bf + (size_t)(slice * 16 + lr) * D : p0bf;

  f32x4 zero4 = {0.f, 0.f, 0.f, 0.f};
  f32x4 acc[8];
  f32x4 zacA = zero4, zacB = zero4;
#pragma unroll
  for (int t = 0; t < 8; ++t) acc[t] = zero4;

  int swz = (lr & 7) << 4;
  int rdb = lr * 512 + kg * 16;

  stage(0, 0);
  __syncthreads();
  int cur = 0;
  for (int c = 0; c < 4; ++c) {            // K chunks of 256
    bf16x8 a[8];
#pragma unroll
    for (int kc = 0; kc < 8; ++kc) {
      int k8 = c * 32 + kc * 4 + kg;
      a[kc] = *(const bf16x8*)(ab + ((r63 * 2048 + k8 * 16) ^ rsw));
    }
#pragma unroll
    for (int t = 0; t < 8; ++t) {
      int p = c * 8 + t;
      if (p + 1 < 32) stage(p + 1, cur ^ 1);
      const char* bb = Bl + cur * 8192;
#pragma unroll
      for (int kc = 0; kc < 8; ++kc) {
        bf16x8 b = *(const bf16x8*)(bb + ((rdb + kc * 64) ^ swz));
        acc[t] = __builtin_amdgcn_mfma_f32_16x16x32_bf16(a[kc], b, acc[t], 0, 0, 0);
      }
      __syncthreads();
      cur ^= 1;
    }
#pragma unroll
    for (int kc = 0; kc < 8; ++kc) {
      bf16x8 bz = *(const bf16x8*)(zbA + c * 256 + kc * 32 + kg * 8);
      zacA = __builtin_amdgcn_mfma_f32_16x16x32_bf16(a[kc], bz, zacA, 0, 0, 0);
    }
    if (hasB) {                            // wave-uniform
#pragma unroll
      for (int kc = 0; kc < 8; ++kc) {
        bf16x8 bz = *(const bf16x8*)(zbB + c * 256 + kc * 32 + kg * 8);
        zacB = __builtin_amdgcn_mfma_f32_16x16x32_bf16(a[kc], bz, zacB, 0, 0, 0);
      }
    }
  }

  // epilogue: sum exp2 over this block's 128 cols (rows owned per wave)
  float s[4] = {};
#pragma unroll
  for (int t = 0; t < 8; ++t)
#pragma unroll
    for (int v = 0; v < 4; ++v) s[v] += __builtin_amdgcn_exp2f(acc[t][v]);
#pragma unroll
  for (int off = 1; off < 16; off <<= 1)
#pragma unroll
    for (int v = 0; v < 4; ++v) s[v] += __shfl_xor(s[v], off);
  if (lr == 0) {
#pragma unroll
    for (int v = 0; v < 4; ++v)
      hs_part[(size_t)slice * N_ROWS + rb * 64 + w * 16 + kg * 4 + v] = s[v];
  }
  // z epilogue: write compacted z rows for this wave's 16 rows
#pragma unroll
  for (int v = 0; v < 4; ++v) {
    int grow = rb * 64 + w * 16 + kg * 4 + v;
    int pcv = posc[grow];
    if (pcv < POS_C1)                      // cluster0 row
      z0[(size_t)pcv * 256 + slice * 16 + lr] = f2bf(zacA[v]);
    if (hasB && pcv != POS_NONE && pcv >= POS_C1)
      z1[(size_t)(pcv & (POS_C1 - 1)) * 64 + slice * 16 + lr] = f2bf(zacB[v]);
  }
}

// --- tails: row-split waves, B staged once per block in LDS (dbuf) --------

__device__ __forceinline__ void tail1_body(int bid, const unsigned short* __restrict__ z,
    const unsigned short* __restrict__ twbf, const int* __restrict__ list,
    const int* __restrict__ cntp, float* __restrict__ ts_part,
    char* __restrict__ Bl) {
  constexpr int MT = T1MP / 16;             // 2517
  constexpr int ST = (MT + SL1 - 1) / SL1;  // 27
  int n = *cntp;
  int rowblock = bid / SL1, slice = bid % SL1;
  int rowbase = rowblock * RPB1;
  if (rowbase >= n) return;                 // block-uniform
  int t0 = slice * ST, t1e = min(t0 + ST, MT);
  if (t0 >= t1e) return;                    // block-uniform
  int tid = threadIdx.x, w = tid >> 6, l = tid & 63, lr = l & 15, kg = l >> 4;

  bf16x8 a[2][2];
#pragma unroll
  for (int rg = 0; rg < 2; ++rg) {
    int idx = min(rowbase + w * 32 + rg * 16 + lr, n - 1);
    const unsigned short* zp = z + (size_t)idx * 64 + kg * 8;
    a[rg][0] = *(const bf16x8*)(zp);
    a[rg][1] = *(const bf16x8*)(zp + 32);
  }

  int sb = tid * 16;
  int stile = sb >> 11, scol = (sb >> 7) & 15;
  int sbyte = (sb & 127) ^ ((scol & 7) << 4);
  const char* tb = (const char*)twbf;
  int mtm1 = MT - 1;
  auto stage = [&](int gt, int buf) {
    int tA = min(gt + stile, mtm1);
    GLOAD_LDS16(tb + (size_t)tA * 2048 + scol * 128 + sbyte, Bl + buf * 4096 + sb);
  };

  int NG = (t1e - t0 + 1) >> 1;
  stage(t0, 0);
  __syncthreads();

  float s[2][4] = {};
  f32x4 zero4 = {0.f, 0.f, 0.f, 0.f};
  int rd0 = (lr * 128 + kg * 16) ^ ((lr & 7) << 4);
  int cur = 0;
  for (int g = 0; g < NG; ++g) {
    int gt = t0 + g * 2;
    if (g + 1 < NG) stage(gt + 2, cur ^ 1);
#pragma unroll
    for (int t = 0; t < 2; ++t) {
      if (gt + t < t1e) {                   // block-uniform guard
        const char* bb = Bl + cur * 4096 + t * 2048;
        bf16x8 b0 = *(const bf16x8*)(bb + rd0);
        bf16x8 b1 = *(const bf16x8*)(bb + (rd0 ^ 64));
        f32x4 acc0 = __builtin_amdgcn_mfma_f32_16x16x32_bf16(a[0][0], b0, zero4, 0, 0, 0);
        f32x4 acc1 = __builtin_amdgcn_mfma_f32_16x16x32_bf16(a[1][0], b0, zero4, 0, 0, 0);
        acc0 = __builtin_amdgcn_mfma_f32_16x16x32_bf16(a[0][1], b1, acc0, 0, 0, 0);
        acc1 = __builtin_amdgcn_mfma_f32_16x16x32_bf16(a[1][1], b1, acc1, 0, 0, 0);
#pragma unroll
        for (int v = 0; v < 4; ++v) {
          s[0][v] += __builtin_amdgcn_exp2f(acc0[v]);
          s[1][v] += __builtin_amdgcn_exp2f(acc1[v]);
        }
      }
    }
    __syncthreads();
    cur ^= 1;
  }

#pragma unroll
  for (int off = 1; off < 16; off <<= 1)
#pragma unroll
    for (int rg = 0; rg < 2; ++rg)
#pragma unroll
      for (int v = 0; v < 4; ++v) s[rg][v] += __shfl_xor(s[rg][v], off);
  if (lr == 0) {
#pragma unroll
    for (int rg = 0; rg < 2; ++rg)
#pragma unroll
      for (int v = 0; v < 4; ++v) {
        int idx = rowbase + w * 32 + rg * 16 + kg * 4 + v;
        if (idx < n)
          ts_part[(size_t)slice * N_ROWS + list[idx]] = s[rg][v];
      }
  }
}

__device__ __forceinline__ void tail0_body(int bid, const unsigned short* __restrict__ z,
    const unsigned short* __restrict__ twbf, const int* __restrict__ list,
    const int* __restrict__ cntp, float* __restrict__ ts_part,
    char* __restrict__ Bl) {
  constexpr int MT = T0MP / 16;             // 500
  constexpr int ST = (MT + SL0 - 1) / SL0;  // 8
  int n = *cntp;
  int rowblock = bid / SL0, slice = bid % SL0;
  int rowbase = rowblock * RPB0;
  if (rowbase >= n) return;
  int t0 = slice * ST, t1e = min(t0 + ST, MT);
  if (t0 >= t1e) return;
  int tid = threadIdx.x, w = tid >> 6, l = tid & 63, lr = l & 15, kg = l >> 4;

  bf16x8 a[8];
  {
    int idx = min(rowbase + w * 16 + lr, n - 1);
    const unsigned short* zp = z + (size_t)idx * 256 + kg * 8;
#pragma unroll
    for (int kc = 0; kc < 8; ++kc) a[kc] = *(const bf16x8*)(zp + kc * 32);
  }

  int sb0 = tid * 16, sb1 = sb0 + 4096;
  int c0s = sb0 >> 9, b0s = (sb0 & 511) ^ ((c0s & 7) << 4);
  int c1s = sb1 >> 9, b1s = (sb1 & 511) ^ ((c1s & 7) << 4);
  const char* tb = (const char*)twbf;
  auto stage = [&](int gt, int buf) {
    GLOAD_LDS16(tb + (size_t)gt * 8192 + c0s * 512 + b0s, Bl + buf * 8192 + sb0);
    GLOAD_LDS16(tb + (size_t)gt * 8192 + c1s * 512 + b1s, Bl + buf * 8192 + sb1);
  };

  int NG = t1e - t0;
  stage(t0, 0);
  __syncthreads();

  float s[4] = {};
  f32x4 zero4 = {0.f, 0.f, 0.f, 0.f};
  int swz = (lr & 7) << 4;
  int rdb = lr * 512 + kg * 16;
  int cur = 0;
  for (int g = 0; g < NG; ++g) {
    if (g + 1 < NG) stage(t0 + g + 1, cur ^ 1);
    const char* bb = Bl + cur * 8192;
    f32x4 acc = zero4;
#pragma unroll
    for (int kc = 0; kc < 8; ++kc) {
      bf16x8 b = *(const bf16x8*)(bb + ((rdb + kc * 64) ^ swz));
      acc = __builtin_amdgcn_mfma_f32_16x16x32_bf16(a[kc], b, acc, 0, 0, 0);
    }
#pragma unroll
    for (int v = 0; v < 4; ++v) s[v] += __builtin_amdgcn_exp2f(acc[v]);
    __syncthreads();
    cur ^= 1;
  }

#pragma unroll
  for (int off = 1; off < 16; off <<= 1)
#pragma unroll
    for (int v = 0; v < 4; ++v) s[v] += __shfl_xor(s[v], off);
  if (lr == 0) {
#pragma unroll
    for (int v = 0; v < 4; ++v) {
      int idx = rowbase + w * 16 + kg * 4 + v;
      if (idx < n)
        ts_part[(size_t)slice * N_ROWS + list[idx]] = s[v];
    }
  }
}

__global__ __launch_bounds__(256, 8) void tf_k(
    const unsigned short* __restrict__ z0, const unsigned short* __restrict__ t0bf,
    const unsigned short* __restrict__ z1, const unsigned short* __restrict__ t1bf,
    const int* __restrict__ l0, const int* __restrict__ l1,
    const int* __restrict__ cnt, float* __restrict__ ts0_part,
    float* __restrict__ ts1_part) {
  __shared__ char Bl[16384];
  int b = blockIdx.x;
  if (b < G_T1)
    tail1_body(b, z1, t1bf, l1, cnt + 1, ts1_part, Bl);
  else
    tail0_body(b - G_T1, z0, t0bf, l0, cnt + 0, ts0_part, Bl);
}

// ---------------- finalize ----------------

__global__ __launch_bounds__(256) void finalize_k(const float* __restrict__ hidden,
    const int* __restrict__ tgt, const float* __restrict__ head_w,
    const float* __restrict__ tail0, const float* __restrict__ tail1,
    const unsigned short* __restrict__ z0, const unsigned short* __restrict__ z1,
    const int* __restrict__ pos, const float* __restrict__ hs_part,
    const float* __restrict__ ts0_part, const float* __restrict__ ts1_part,
    float* __restrict__ out) {
  int w = threadIdx.x >> 6, l = threadIdx.x & 63;
  int row = blockIdx.x * 4 + w;
  int t = tgt[row];
  int jt = t < 0 ? 0 : (t < CUT0 ? t : (t < CUT1 ? CUT0 : CUT0 + 1));
  const float4* h4 = (const float4*)(hidden + (size_t)row * D);
  const float4* w4 = (const float4*)(head_w + (size_t)jt * D);
  float acc = 0.f;
#pragma unroll
  for (int j = 0; j < 4; ++j) {
    float4 a = h4[l + 64 * j], b = w4[l + 64 * j];
    acc += a.x * b.x + a.y * b.y + a.z * b.z + a.w * b.w;
  }
  float hp = (l < HSL) ? hs_part[(size_t)l * N_ROWS + row] : 0.f;
#pragma unroll
  for (int off = 32; off; off >>= 1) {
    acc += __shfl_xor(acc, off);
    hp  += __shfl_xor(hp, off);
  }
  float val = acc - __logf(hp - 46.f);      // subtract 46 zero-pad cols
  if (t >= CUT0) {
    int p = pos[row] & (POS_C1 - 1);
    float ta = 0.f, tp = 0.f;
    if (t < CUT1) {
      const unsigned short* zr = z0 + (size_t)p * 256;
      const float* tw = tail0 + (size_t)(t - CUT0) * 256;
#pragma unroll
      for (int j = 0; j < 4; ++j) ta += bf2f(zr[l + 64 * j]) * tw[l + 64 * j];
      tp = ts0_part[(size_t)l * N_ROWS + row];            // SL0 = 64 slices
    } else {
      const unsigned short* zr = z1 + (size_t)p * 64;
      const float* tw = tail1 + (size_t)(t - CUT1) * 64;
      ta = bf2f(zr[l]) * tw[l];
      tp = ts1_part[(size_t)l * N_ROWS + row];            // slices 0..63
      if (l < SL1 - 64) tp += ts1_part[(size_t)(64 + l) * N_ROWS + row];
    }
#pragma unroll
    for (int off = 32; off; off >>= 1) {
      ta += __shfl_xor(ta, off);
      tp += __shfl_xor(tp, off);
    }
    float lt = tp - ((t >= CUT1) ? 15.f : 0.f);  // subtract zero-pad cols
    val += ta - __logf(lt);
  }
  if (l == 0) out[row] = (t < 0) ? 0.f : val;
}

// ---------------- loss ----------------

__global__ __launch_bounds__(256) void loss_k(const float* __restrict__ out,
                                              const int* __restrict__ target,
                                              float* __restrict__ loss) {
  __shared__ float ssum[256];
  __shared__ int scnt[256];
  float s = 0.f; int c = 0;
  for (int i = threadIdx.x; i < N_ROWS; i += 256) {
    s += out[i];
    if (target[i] >= 0) c++;
  }
  ssum[threadIdx.x] = s; scnt[threadIdx.x] = c;
  __syncthreads();
  for (int off = 128; off; off >>= 1) {
    if (threadIdx.x < off) {
      ssum[threadIdx.x] += ssum[threadIdx.x + off];
      scnt[threadIdx.x] += scnt[threadIdx.x + off];
    }
    __syncthreads();
  }
  if (threadIdx.x == 0) {
    int nv = scnt[0];
    loss[0] = (nv > 0) ? (-ssum[0] / (float)nv) : 0.f;
  }
}

// ---------------- launch ----------------

extern "C" void kernel_launch(void* const* d_in, const int* in_sizes, int n_in,
                              void* d_out, int out_size, void* d_ws, size_t ws_size,
                              hipStream_t stream) {
  const float* hidden = (const float*)d_in[0];
  const int*   target = (const int*)d_in[1];
  const float* head_w = (const float*)d_in[2];
  const float* proj0  = (const float*)d_in[3];
  const float* tail0  = (const float*)d_in[4];
  const float* proj1  = (const float*)d_in[5];
  const float* tail1  = (const float*)d_in[6];
  float* out = (float*)d_out;

  char* wp = (char*)d_ws;
  auto alloc = [&](size_t bytes) {
    char* p = wp;
    wp += (bytes + 255) & ~(size_t)255;
    return p;
  };
  int* cnt   = (int*)alloc(8);
  int* list0 = (int*)alloc(N_ROWS * 4);
  int* list1 = (int*)alloc(N_ROWS * 4);
  int* pos   = (int*)alloc(N_ROWS * 4);
  unsigned short* hbf  = (unsigned short*)alloc((size_t)N_ROWS * D * 2);
  unsigned short* hwbf = (unsigned short*)alloc((size_t)HMP * D * 2);
  unsigned short* t0bf = (unsigned short*)alloc((size_t)T0MP * 256 * 2);
  unsigned short* t1bf = (unsigned short*)alloc((size_t)T1MP * 64 * 2);
  unsigned short* p0bf = (unsigned short*)alloc((size_t)256 * D * 2);
  unsigned short* p1bf = (unsigned short*)alloc((size_t)64 * D * 2);
  unsigned short* z0   = (unsigned short*)alloc((size_t)N_ROWS * 256 * 2);
  unsigned short* z1   = (unsigned short*)alloc((size_t)N_ROWS * 64 * 2);
  float* hs_part  = (float*)alloc((size_t)HSL * N_ROWS * 4);
  float* ts0_part = (float*)alloc((size_t)SL0 * N_ROWS * 4);
  float* ts1_part = (float*)alloc((size_t)SL1 * N_ROWS * 4);

  prep_k<<<NCONV + 1, 256, 0, stream>>>(hidden, head_w, tail0, tail1, proj0, proj1,
                                        hbf, hwbf, t0bf, t1bf, p0bf, p1bf,
                                        target, cnt, list0, list1, pos);
  headk_k<<<G_HK, 256, 0, stream>>>(hbf, hwbf, p0bf, p1bf, pos, z0, z1, hs_part);
  tf_k<<<G_T1 + G_T0, 256, 0, stream>>>(z0, t0bf, z1, t1bf, list0, list1, cnt,
                                        ts0_part, ts1_part);
  finalize_k<<<N_ROWS / 4, 256, 0, stream>>>(hidden, target, head_w, tail0, tail1,
                                             z0, z1, pos, hs_part, ts0_part, ts1_part, out);
  loss_k<<<1, 256, 0, stream>>>(out, target, out + N_ROWS);
}

// Round 21
// 116.470 us; speedup vs baseline: 1.2039x; 1.0643x over previous
//
#include <hip/hip_runtime.h>
#include <math.h>

using f32x4  = __attribute__((ext_vector_type(4))) float;
using bf16x8 = __attribute__((ext_vector_type(8))) short;

#define GLOAD_LDS16(gp, lp)                                            \
  __builtin_amdgcn_global_load_lds(                                    \
      (const __attribute__((address_space(1))) void*)(gp),             \
      (__attribute__((address_space(3))) void*)(lp), 16, 0, 0)

namespace {
constexpr int N_ROWS = 4096;
constexpr int D      = 1024;
constexpr int CUT0   = 2000, CUT1 = 10000, VTOT = 50257;
constexpr int HM   = 2002;                 // head cols (2000 + 2 cluster)
constexpr int HMP  = 2048;                 // padded head cols (pad = 46)
constexpr int T0M  = 8000,              T0MP = 8000;    // pad 0
constexpr int T1M  = VTOT - CUT1;                        // 40257
constexpr int T1MP = 40272;                              // pad 15
constexpr float LOG2E = 1.4426950408889634f;
constexpr int POS_NONE = 0x7FFFFFFF;
constexpr int POS_C1   = 1 << 30;
// tails: row-split waves, B shared via LDS double-buffer
constexpr int SL1 = 96, SL0 = 64;
constexpr int RPB1 = 128, RPB0 = 64;       // rows per block (32 / 16 per wave)
constexpr int G_T1 = (N_ROWS / RPB1) * SL1;       // 3072 blocks (worst case)
constexpr int G_T0 = (N_ROWS / RPB0) * SL0;       // 4096 blocks (worst case)
// fused-convert region boundaries (elements): hidden first, then weights
constexpr long long BH = (long long)N_ROWS * D;
constexpr long long B0 = (long long)HMP * D;
constexpr long long B1 = B0 + (long long)T0MP * 256;
constexpr long long B2 = B1 + (long long)T1MP * 64;
constexpr long long B3 = B2 + (long long)256 * D;
constexpr long long B4 = B3 + (long long)64 * D;
constexpr long long TOT = BH + B4;
constexpr int NCONV = (int)((TOT / 8 + 255) / 256);   // convert blocks
}

__device__ __forceinline__ unsigned short f2bf(float x) {
  unsigned u = __builtin_bit_cast(unsigned, x);
  u += 0x7FFFu + ((u >> 16) & 1u);
  return (unsigned short)(u >> 16);
}
__device__ __forceinline__ float bf2f(unsigned short b) {
  unsigned u = ((unsigned)b) << 16;
  return __builtin_bit_cast(float, u);
}
__device__ __forceinline__ bf16x8 pack8(float4 f0, float4 f1, float sc) {
  bf16x8 o;
  o[0] = f2bf(f0.x * sc); o[1] = f2bf(f0.y * sc);
  o[2] = f2bf(f0.z * sc); o[3] = f2bf(f0.w * sc);
  o[4] = f2bf(f1.x * sc); o[5] = f2bf(f1.y * sc);
  o[6] = f2bf(f1.z * sc); o[7] = f2bf(f1.w * sc);
  return o;
}

// ---- prep: fused converts (hidden swizzled-bf16 + all weights) + scan ----

__global__ __launch_bounds__(256) void prep_k(
    const float* __restrict__ hidden, const float* __restrict__ hw,
    const float* __restrict__ t0, const float* __restrict__ t1,
    const float* __restrict__ p0, const float* __restrict__ p1,
    unsigned short* __restrict__ hbf, unsigned short* __restrict__ dhw,
    unsigned short* __restrict__ dt0, unsigned short* __restrict__ dt1,
    unsigned short* __restrict__ dp0, unsigned short* __restrict__ dp1,
    const int* __restrict__ tgt, int* __restrict__ cnt,
    int* __restrict__ l0, int* __restrict__ l1, int* __restrict__ pos) {
  if (blockIdx.x == NCONV) {              // last block: compaction scan
    __shared__ int s0[256], s1[256];
    int tid = threadIdx.x;
    int c0 = 0, c1 = 0;
#pragma unroll
    for (int j = 0; j < 16; ++j) {
      int v = tgt[tid * 16 + j];
      c0 += (v >= CUT0 && v < CUT1);
      c1 += (v >= CUT1);
    }
    s0[tid] = c0; s1[tid] = c1;
    __syncthreads();
    for (int off = 1; off < 256; off <<= 1) {
      int a0 = (tid >= off) ? s0[tid - off] : 0;
      int a1 = (tid >= off) ? s1[tid - off] : 0;
      __syncthreads();
      s0[tid] += a0; s1[tid] += a1;
      __syncthreads();
    }
    int b0 = s0[tid] - c0, b1 = s1[tid] - c1;
#pragma unroll
    for (int j = 0; j < 16; ++j) {
      int row = tid * 16 + j;
      int v = tgt[row];
      if (v >= CUT0 && v < CUT1)      { l0[b0] = row; pos[row] = b0; ++b0; }
      else if (v >= CUT1)             { l1[b1] = row; pos[row] = b1 | POS_C1; ++b1; }
      else                            { pos[row] = POS_NONE; }
    }
    if (tid == 255) { cnt[0] = s0[255]; cnt[1] = s1[255]; }
    return;
  }
  long long i = ((long long)blockIdx.x * 256 + threadIdx.x) * 8;
  if (i >= TOT) return;
  if (i < BH) {                           // hidden -> swizzled bf16 tiles
    int c = (int)(i >> 3);
    int row = c >> 7, k8 = c & 127;
    const float* hp = hidden + (size_t)row * D + k8 * 8;
    float4 f0 = *(const float4*)hp, f1 = *(const float4*)(hp + 4);
    bf16x8 o = pack8(f0, f1, 1.f);
    size_t tb = (size_t)(row >> 6) * 131072;
    int boff = (((row & 63) * 2048 + k8 * 16) ^ ((row & 7) << 4));
    *(bf16x8*)((char*)hbf + tb + boff) = o;
    return;
  }
  long long j = i - BH;
  const float* src; unsigned short* dst; long long off, nsrc;
  float scale = LOG2E;
  if (j < B0)      { src = hw; dst = dhw; off = j;      nsrc = (long long)HM * D; }
  else if (j < B1) { src = t0; dst = dt0; off = j - B0; nsrc = (long long)T0M * 256; }
  else if (j < B2) { src = t1; dst = dt1; off = j - B1; nsrc = (long long)T1M * 64; }
  else if (j < B3) { src = p0; dst = dp0; off = j - B2; nsrc = (long long)256 * D; scale = 1.f; }
  else             { src = p1; dst = dp1; off = j - B3; nsrc = (long long)64 * D;  scale = 1.f; }
  bf16x8 o;
  if (off < nsrc) {   // region sizes and nsrc are multiples of 8
    float4 f0 = *(const float4*)(src + off), f1 = *(const float4*)(src + off + 4);
    o = pack8(f0, f1, scale);
  } else {
    o = bf16x8{0, 0, 0, 0, 0, 0, 0, 0};
  }
  *(bf16x8*)(dst + off) = o;
}

// ------ headz: 1024 threads (16 waves -> 4/SIMD), 64-row swizzled A-LDS,
// ------ each wave owns 2 head col-tiles + optional z tile ----------------

__global__ __launch_bounds__(1024) void headz_k(const unsigned short* __restrict__ hbf,
    const unsigned short* __restrict__ hwbf, const unsigned short* __restrict__ p0bf,
    const unsigned short* __restrict__ p1bf, const int* __restrict__ posc,
    unsigned short* __restrict__ z0, unsigned short* __restrict__ z1,
    float* __restrict__ hs_part) {
  __shared__ char Ab[64 * 2048];            // 128 KB swizzled bf16 (pre-baked)
  __shared__ float red[16][64];
  int rb = blockIdx.x >> 2, slice = blockIdx.x & 3;
  int tid = threadIdx.x;

  const bf16x8* src = (const bf16x8*)(hbf + (size_t)rb * 65536);
  bf16x8* dstv = (bf16x8*)Ab;
#pragma unroll
  for (int j = 0; j < 8; ++j) dstv[j * 1024 + tid] = src[j * 1024 + tid];
  __syncthreads();

  int w = tid >> 6, l = tid & 63, lr = l & 15, kg = l >> 4;
  int tg0 = (slice * 16 + w) * 2;           // this wave's 2 head col-tiles
  int zt = slice * 16 + w;                  // this wave's z col-tile (if <20)
  bool hasz = zt < 20;
  const unsigned short* zb = hasz
      ? (zt < 16 ? p0bf + (size_t)(zt * 16 + lr) * D
                 : p1bf + (size_t)((zt - 16) * 16 + lr) * D)
      : p0bf;
  f32x4 zero4 = {0.f, 0.f, 0.f, 0.f};
  f32x4 acc[4][2];                          // [rowgroup][tile]
  f32x4 zac[4];
#pragma unroll
  for (int rg = 0; rg < 4; ++rg) {
    zac[rg] = zero4;
#pragma unroll
    for (int t = 0; t < 2; ++t) acc[rg][t] = zero4;
  }

#pragma unroll 4
  for (int kc = 0; kc < 32; ++kc) {
    bf16x8 af[4], bf[2];
#pragma unroll
    for (int rg = 0; rg < 4; ++rg) {
      int addr = ((rg * 16 + lr) * 2048 + kc * 64 + kg * 16) ^ ((lr & 7) << 4);
      af[rg] = *(const bf16x8*)(Ab + addr);
    }
#pragma unroll
    for (int t = 0; t < 2; ++t)
      bf[t] = *(const bf16x8*)(hwbf + (size_t)((tg0 + t) * 16 + lr) * D + kc * 32 + kg * 8);
#pragma unroll
    for (int rg = 0; rg < 4; ++rg)
#pragma unroll
      for (int t = 0; t < 2; ++t)
        acc[rg][t] = __builtin_amdgcn_mfma_f32_16x16x32_bf16(af[rg], bf[t], acc[rg][t], 0, 0, 0);
    if (hasz) {                             // wave-uniform branch
      bf16x8 bz = *(const bf16x8*)(zb + kc * 32 + kg * 8);
#pragma unroll
      for (int rg = 0; rg < 4; ++rg)
        zac[rg] = __builtin_amdgcn_mfma_f32_16x16x32_bf16(af[rg], bz, zac[rg], 0, 0, 0);
    }
  }

  // head epilogue: sum exp2 over this wave's 32 cols
  float sv[4][4];
#pragma unroll
  for (int rg = 0; rg < 4; ++rg)
#pragma unroll
    for (int v = 0; v < 4; ++v) {
      float s = 0.f;
#pragma unroll
      for (int t = 0; t < 2; ++t) s += __builtin_amdgcn_exp2f(acc[rg][t][v]);
      sv[rg][v] = s;
    }
#pragma unroll
  for (int off = 1; off < 16; off <<= 1)
#pragma unroll
    for (int rg = 0; rg < 4; ++rg)
#pragma unroll
      for (int v = 0; v < 4; ++v) sv[rg][v] += __shfl_xor(sv[rg][v], off);
  if (lr == 0)
#pragma unroll
    for (int rg = 0; rg < 4; ++rg)
#pragma unroll
      for (int v = 0; v < 4; ++v) red[w][rg * 16 + kg * 4 + v] = sv[rg][v];

  // z epilogue: write compacted z rows (cluster-matched only)
  if (hasz) {
#pragma unroll
    for (int rg = 0; rg < 4; ++rg)
#pragma unroll
      for (int v = 0; v < 4; ++v) {
        int grow = rb * 64 + rg * 16 + kg * 4 + v;
        int pcv = posc[grow];
        if (zt < 16) {
          if (pcv < POS_C1)
            z0[(size_t)pcv * 256 + zt * 16 + lr] = f2bf(zac[rg][v]);
        } else {
          if (pcv != POS_NONE && pcv >= POS_C1)
            z1[(size_t)(pcv & (POS_C1 - 1)) * 64 + (zt - 16) * 16 + lr] = f2bf(zac[rg][v]);
        }
      }
  }
  __syncthreads();
  if (tid < 64) {
    float s = 0.f;
#pragma unroll
    for (int ww = 0; ww < 16; ++ww) s += red[ww][tid];
    hs_part[slice * N_ROWS + rb * 64 + tid] = s;
  }
}

// --- tails: row-split waves, B staged once per block in LDS (dbuf) --------

__device__ __forceinline__ void tail1_body(int bid, const unsigned short* __restrict__ z,
    const unsigned short* __restrict__ twbf, const int* __restrict__ list,
    const int* __restrict__ cntp, float* __restrict__ ts_part,
    char* __restrict__ Bl) {
  constexpr int MT = T1MP / 16;             // 2517
  constexpr int ST = (MT + SL1 - 1) / SL1;  // 27
  int n = *cntp;
  int rowblock = bid / SL1, slice = bid % SL1;
  int rowbase = rowblock * RPB1;
  if (rowbase >= n) return;                 // block-uniform
  int t0 = slice * ST, t1e = min(t0 + ST, MT);
  if (t0 >= t1e) return;                    // block-uniform
  int tid = threadIdx.x, w = tid >> 6, l = tid & 63, lr = l & 15, kg = l >> 4;

  bf16x8 a[2][2];
#pragma unroll
  for (int rg = 0; rg < 2; ++rg) {
    int idx = min(rowbase + w * 32 + rg * 16 + lr, n - 1);
    const unsigned short* zp = z + (size_t)idx * 64 + kg * 8;
    a[rg][0] = *(const bf16x8*)(zp);
    a[rg][1] = *(const bf16x8*)(zp + 32);
  }

  int sb = tid * 16;
  int stile = sb >> 11, scol = (sb >> 7) & 15;
  int sbyte = (sb & 127) ^ ((scol & 7) << 4);
  const char* tb = (const char*)twbf;
  int mtm1 = MT - 1;
  auto stage = [&](int gt, int buf) {
    int tA = min(gt + stile, mtm1);
    GLOAD_LDS16(tb + (size_t)tA * 2048 + scol * 128 + sbyte, Bl + buf * 4096 + sb);
  };

  int NG = (t1e - t0 + 1) >> 1;
  stage(t0, 0);
  __syncthreads();

  float s[2][4] = {};
  f32x4 zero4 = {0.f, 0.f, 0.f, 0.f};
  int rd0 = (lr * 128 + kg * 16) ^ ((lr & 7) << 4);
  int cur = 0;
  for (int g = 0; g < NG; ++g) {
    int gt = t0 + g * 2;
    if (g + 1 < NG) stage(gt + 2, cur ^ 1);
#pragma unroll
    for (int t = 0; t < 2; ++t) {
      if (gt + t < t1e) {                   // block-uniform guard
        const char* bb = Bl + cur * 4096 + t * 2048;
        bf16x8 b0 = *(const bf16x8*)(bb + rd0);
        bf16x8 b1 = *(const bf16x8*)(bb + (rd0 ^ 64));
        f32x4 acc0 = __builtin_amdgcn_mfma_f32_16x16x32_bf16(a[0][0], b0, zero4, 0, 0, 0);
        f32x4 acc1 = __builtin_amdgcn_mfma_f32_16x16x32_bf16(a[1][0], b0, zero4, 0, 0, 0);
        acc0 = __builtin_amdgcn_mfma_f32_16x16x32_bf16(a[0][1], b1, acc0, 0, 0, 0);
        acc1 = __builtin_amdgcn_mfma_f32_16x16x32_bf16(a[1][1], b1, acc1, 0, 0, 0);
#pragma unroll
        for (int v = 0; v < 4; ++v) {
          s[0][v] += __builtin_amdgcn_exp2f(acc0[v]);
          s[1][v] += __builtin_amdgcn_exp2f(acc1[v]);
        }
      }
    }
    __syncthreads();
    cur ^= 1;
  }

#pragma unroll
  for (int off = 1; off < 16; off <<= 1)
#pragma unroll
    for (int rg = 0; rg < 2; ++rg)
#pragma unroll
      for (int v = 0; v < 4; ++v) s[rg][v] += __shfl_xor(s[rg][v], off);
  if (lr == 0) {
#pragma unroll
    for (int rg = 0; rg < 2; ++rg)
#pragma unroll
      for (int v = 0; v < 4; ++v) {
        int idx = rowbase + w * 32 + rg * 16 + kg * 4 + v;
        if (idx < n)
          ts_part[(size_t)slice * N_ROWS + list[idx]] = s[rg][v];
      }
  }
}

__device__ __forceinline__ void tail0_body(int bid, const unsigned short* __restrict__ z,
    const unsigned short* __restrict__ twbf, const int* __restrict__ list,
    const int* __restrict__ cntp, float* __restrict__ ts_part,
    char* __restrict__ Bl) {
  constexpr int MT = T0MP / 16;             // 500
  constexpr int ST = (MT + SL0 - 1) / SL0;  // 8
  int n = *cntp;
  int rowblock = bid / SL0, slice = bid % SL0;
  int rowbase = rowblock * RPB0;
  if (rowbase >= n) return;
  int t0 = slice * ST, t1e = min(t0 + ST, MT);
  if (t0 >= t1e) return;
  int tid = threadIdx.x, w = tid >> 6, l = tid & 63, lr = l & 15, kg = l >> 4;

  bf16x8 a[8];
  {
    int idx = min(rowbase + w * 16 + lr, n - 1);
    const unsigned short* zp = z + (size_t)idx * 256 + kg * 8;
#pragma unroll
    for (int kc = 0; kc < 8; ++kc) a[kc] = *(const bf16x8*)(zp + kc * 32);
  }

  int sb0 = tid * 16, sb1 = sb0 + 4096;
  int c0s = sb0 >> 9, b0s = (sb0 & 511) ^ ((c0s & 7) << 4);
  int c1s = sb1 >> 9, b1s = (sb1 & 511) ^ ((c1s & 7) << 4);
  const char* tb = (const char*)twbf;
  auto stage = [&](int gt, int buf) {
    GLOAD_LDS16(tb + (size_t)gt * 8192 + c0s * 512 + b0s, Bl + buf * 8192 + sb0);
    GLOAD_LDS16(tb + (size_t)gt * 8192 + c1s * 512 + b1s, Bl + buf * 8192 + sb1);
  };

  int NG = t1e - t0;
  stage(t0, 0);
  __syncthreads();

  float s[4] = {};
  f32x4 zero4 = {0.f, 0.f, 0.f, 0.f};
  int swz = (lr & 7) << 4;
  int rdb = lr * 512 + kg * 16;
  int cur = 0;
  for (int g = 0; g < NG; ++g) {
    if (g + 1 < NG) stage(t0 + g + 1, cur ^ 1);
    const char* bb = Bl + cur * 8192;
    f32x4 acc = zero4;
#pragma unroll
    for (int kc = 0; kc < 8; ++kc) {
      bf16x8 b = *(const bf16x8*)(bb + ((rdb + kc * 64) ^ swz));
      acc = __builtin_amdgcn_mfma_f32_16x16x32_bf16(a[kc], b, acc, 0, 0, 0);
    }
#pragma unroll
    for (int v = 0; v < 4; ++v) s[v] += __builtin_amdgcn_exp2f(acc[v]);
    __syncthreads();
    cur ^= 1;
  }

#pragma unroll
  for (int off = 1; off < 16; off <<= 1)
#pragma unroll
    for (int v = 0; v < 4; ++v) s[v] += __shfl_xor(s[v], off);
  if (lr == 0) {
#pragma unroll
    for (int v = 0; v < 4; ++v) {
      int idx = rowbase + w * 16 + kg * 4 + v;
      if (idx < n)
        ts_part[(size_t)slice * N_ROWS + list[idx]] = s[v];
    }
  }
}

__global__ __launch_bounds__(256, 8) void tf_k(
    const unsigned short* __restrict__ z0, const unsigned short* __restrict__ t0bf,
    const unsigned short* __restrict__ z1, const unsigned short* __restrict__ t1bf,
    const int* __restrict__ l0, const int* __restrict__ l1,
    const int* __restrict__ cnt, float* __restrict__ ts0_part,
    float* __restrict__ ts1_part) {
  __shared__ char Bl[16384];
  int b = blockIdx.x;
  if (b < G_T1)
    tail1_body(b, z1, t1bf, l1, cnt + 1, ts1_part, Bl);
  else
    tail0_body(b - G_T1, z0, t0bf, l0, cnt + 0, ts0_part, Bl);
}

// ---------------- finalize ----------------

__global__ __launch_bounds__(256) void finalize_k(const float* __restrict__ hidden,
    const int* __restrict__ tgt, const float* __restrict__ head_w,
    const float* __restrict__ tail0, const float* __restrict__ tail1,
    const unsigned short* __restrict__ z0, const unsigned short* __restrict__ z1,
    const int* __restrict__ pos, const float* __restrict__ hs_part,
    const float* __restrict__ ts0_part, const float* __restrict__ ts1_part,
    float* __restrict__ out) {
  int w = threadIdx.x >> 6, l = threadIdx.x & 63;
  int row = blockIdx.x * 4 + w;
  int t = tgt[row];
  int jt = t < 0 ? 0 : (t < CUT0 ? t : (t < CUT1 ? CUT0 : CUT0 + 1));
  const float4* h4 = (const float4*)(hidden + (size_t)row * D);
  const float4* w4 = (const float4*)(head_w + (size_t)jt * D);
  float acc = 0.f;
#pragma unroll
  for (int j = 0; j < 4; ++j) {
    float4 a = h4[l + 64 * j], b = w4[l + 64 * j];
    acc += a.x * b.x + a.y * b.y + a.z * b.z + a.w * b.w;
  }
  float hp = (l < 4) ? hs_part[l * N_ROWS + row] : 0.f;
#pragma unroll
  for (int off = 32; off; off >>= 1) {
    acc += __shfl_xor(acc, off);
    hp  += __shfl_xor(hp, off);
  }
  float val = acc - __logf(hp - 46.f);      // subtract 46 zero-pad cols
  if (t >= CUT0) {
    int p = pos[row] & (POS_C1 - 1);
    float ta = 0.f, tp = 0.f;
    if (t < CUT1) {
      const unsigned short* zr = z0 + (size_t)p * 256;
      const float* tw = tail0 + (size_t)(t - CUT0) * 256;
#pragma unroll
      for (int j = 0; j < 4; ++j) ta += bf2f(zr[l + 64 * j]) * tw[l + 64 * j];
      tp = ts0_part[(size_t)l * N_ROWS + row];            // SL0 = 64 slices
    } else {
      const unsigned short* zr = z1 + (size_t)p * 64;
      const float* tw = tail1 + (size_t)(t - CUT1) * 64;
      ta = bf2f(zr[l]) * tw[l];
      tp = ts1_part[(size_t)l * N_ROWS + row];            // slices 0..63
      if (l < SL1 - 64) tp += ts1_part[(size_t)(64 + l) * N_ROWS + row];
    }
#pragma unroll
    for (int off = 32; off; off >>= 1) {
      ta += __shfl_xor(ta, off);
      tp += __shfl_xor(tp, off);
    }
    float lt = tp - ((t >= CUT1) ? 15.f : 0.f);  // subtract zero-pad cols
    val += ta - __logf(lt);
  }
  if (l == 0) out[row] = (t < 0) ? 0.f : val;
}

// ---------------- loss ----------------

__global__ __launch_bounds__(256) void loss_k(const float* __restrict__ out,
                                              const int* __restrict__ target,
                                              float* __restrict__ loss) {
  __shared__ float ssum[256];
  __shared__ int scnt[256];
  float s = 0.f; int c = 0;
  for (int i = threadIdx.x; i < N_ROWS; i += 256) {
    s += out[i];
    if (target[i] >= 0) c++;
  }
  ssum[threadIdx.x] = s; scnt[threadIdx.x] = c;
  __syncthreads();
  for (int off = 128; off; off >>= 1) {
    if (threadIdx.x < off) {
      ssum[threadIdx.x] += ssum[threadIdx.x + off];
      scnt[threadIdx.x] += scnt[threadIdx.x + off];
    }
    __syncthreads();
  }
  if (threadIdx.x == 0) {
    int nv = scnt[0];
    loss[0] = (nv > 0) ? (-ssum[0] / (float)nv) : 0.f;
  }
}

// ---------------- launch ----------------

extern "C" void kernel_launch(void* const* d_in, const int* in_sizes, int n_in,
                              void* d_out, int out_size, void* d_ws, size_t ws_size,
                              hipStream_t stream) {
  const float* hidden = (const float*)d_in[0];
  const int*   target = (const int*)d_in[1];
  const float* head_w = (const float*)d_in[2];
  const float* proj0  = (const float*)d_in[3];
  const float* tail0  = (const float*)d_in[4];
  const float* proj1  = (const float*)d_in[5];
  const float* tail1  = (const float*)d_in[6];
  float* out = (float*)d_out;

  char* wp = (char*)d_ws;
  auto alloc = [&](size_t bytes) {
    char* p = wp;
    wp += (bytes + 255) & ~(size_t)255;
    return p;
  };
  int* cnt   = (int*)alloc(8);
  int* list0 = (int*)alloc(N_ROWS * 4);
  int* list1 = (int*)alloc(N_ROWS * 4);
  int* pos   = (int*)alloc(N_ROWS * 4);
  unsigned short* hbf  = (unsigned short*)alloc((size_t)N_ROWS * D * 2);
  unsigned short* hwbf = (unsigned short*)alloc((size_t)HMP * D * 2);
  unsigned short* t0bf = (unsigned short*)alloc((size_t)T0MP * 256 * 2);
  unsigned short* t1bf = (unsigned short*)alloc((size_t)T1MP * 64 * 2);
  unsigned short* p0bf = (unsigned short*)alloc((size_t)256 * D * 2);
  unsigned short* p1bf = (unsigned short*)alloc((size_t)64 * D * 2);
  unsigned short* z0   = (unsigned short*)alloc((size_t)N_ROWS * 256 * 2);
  unsigned short* z1   = (unsigned short*)alloc((size_t)N_ROWS * 64 * 2);
  float* hs_part  = (float*)alloc((size_t)4 * N_ROWS * 4);
  float* ts0_part = (float*)alloc((size_t)SL0 * N_ROWS * 4);
  float* ts1_part = (float*)alloc((size_t)SL1 * N_ROWS * 4);

  prep_k<<<NCONV + 1, 256, 0, stream>>>(hidden, head_w, tail0, tail1, proj0, proj1,
                                        hbf, hwbf, t0bf, t1bf, p0bf, p1bf,
                                        target, cnt, list0, list1, pos);
  headz_k<<<(N_ROWS / 64) * 4, 1024, 0, stream>>>(hbf, hwbf, p0bf, p1bf, pos,
                                                  z0, z1, hs_part);
  tf_k<<<G_T1 + G_T0, 256, 0, stream>>>(z0, t0bf, z1, t1bf, list0, list1, cnt,
                                        ts0_part, ts1_part);
  finalize_k<<<N_ROWS / 4, 256, 0, stream>>>(hidden, target, head_w, tail0, tail1,
                                             z0, z1, pos, hs_part, ts0_part, ts1_part, out);
  loss_k<<<1, 256, 0, stream>>>(out, target, out + N_ROWS);
}

// Round 22
// 101.282 us; speedup vs baseline: 1.3844x; 1.1500x over previous
//
#include <hip/hip_runtime.h>
#include <math.h>

using f32x4  = __attribute__((ext_vector_type(4))) float;
using bf16x8 = __attribute__((ext_vector_type(8))) short;

#define GLOAD_LDS16(gp, lp)                                            \
  __builtin_amdgcn_global_load_lds(                                    \
      (const __attribute__((address_space(1))) void*)(gp),             \
      (__attribute__((address_space(3))) void*)(lp), 16, 0, 0)

namespace {
constexpr int N_ROWS = 4096;
constexpr int D      = 1024;
constexpr int CUT0   = 2000, CUT1 = 10000, VTOT = 50257;
constexpr int HM   = 2002;                 // head cols (2000 + 2 cluster)
constexpr int HMP  = 2048;                 // padded head cols (pad = 46)
constexpr int T0M  = 8000,              T0MP = 8000;    // pad 0
constexpr int T1M  = VTOT - CUT1;                        // 40257
constexpr int T1MP = 40272;                              // pad 15
constexpr float LOG2E = 1.4426950408889634f;
constexpr int POS_NONE = 0x7FFFFFFF;
constexpr int POS_C1   = 1 << 30;
// tails: row-split waves, B shared via LDS double-buffer
constexpr int SL1 = 96, SL0 = 64;
constexpr int RPB1 = 128, RPB0 = 64;       // rows per block (32 / 16 per wave)
constexpr int G_T1 = (N_ROWS / RPB1) * SL1;       // 3072 blocks (worst case)
constexpr int G_T0 = (N_ROWS / RPB0) * SL0;       // 4096 blocks (worst case)
// fused-convert region boundaries (elements): hidden first, then weights
constexpr long long BH = (long long)N_ROWS * D;
constexpr long long B0 = (long long)HMP * D;
constexpr long long B1 = B0 + (long long)T0MP * 256;
constexpr long long B2 = B1 + (long long)T1MP * 64;
constexpr long long B3 = B2 + (long long)256 * D;
constexpr long long B4 = B3 + (long long)64 * D;
constexpr long long TOT = BH + B4;
constexpr int NCONV = (int)((TOT / 8 + 255) / 256);   // convert blocks
}

__device__ __forceinline__ unsigned short f2bf(float x) {
  unsigned u = __builtin_bit_cast(unsigned, x);
  u += 0x7FFFu + ((u >> 16) & 1u);
  return (unsigned short)(u >> 16);
}
__device__ __forceinline__ float bf2f(unsigned short b) {
  unsigned u = ((unsigned)b) << 16;
  return __builtin_bit_cast(float, u);
}
__device__ __forceinline__ bf16x8 pack8(float4 f0, float4 f1, float sc) {
  bf16x8 o;
  o[0] = f2bf(f0.x * sc); o[1] = f2bf(f0.y * sc);
  o[2] = f2bf(f0.z * sc); o[3] = f2bf(f0.w * sc);
  o[4] = f2bf(f1.x * sc); o[5] = f2bf(f1.y * sc);
  o[6] = f2bf(f1.z * sc); o[7] = f2bf(f1.w * sc);
  return o;
}
// fragment-transposed dst index (elements) for source (c,k), k%8==0:
// tile=c>>4, lr=c&15, kc=k>>5, kg=(k>>3)&3, lane=kg*16+lr
__device__ __forceinline__ size_t fragT(int c, int k) {
  int t = c >> 4, lr = c & 15, kc = k >> 5, kg = (k >> 3) & 3;
  return ((size_t)(t * 32 + kc)) * 512 + (kg * 16 + lr) * 8;
}

// ---- prep: fused converts (hidden swizzled-bf16 + frag-transposed head/proj
// ----       weights + linear tail weights) + compaction scan --------------

__global__ __launch_bounds__(256) void prep_k(
    const float* __restrict__ hidden, const float* __restrict__ hw,
    const float* __restrict__ t0, const float* __restrict__ t1,
    const float* __restrict__ p0, const float* __restrict__ p1,
    unsigned short* __restrict__ hbf, unsigned short* __restrict__ dhw,
    unsigned short* __restrict__ dt0, unsigned short* __restrict__ dt1,
    unsigned short* __restrict__ dp0, unsigned short* __restrict__ dp1,
    const int* __restrict__ tgt, int* __restrict__ cnt,
    int* __restrict__ l0, int* __restrict__ l1, int* __restrict__ pos) {
  if (blockIdx.x == NCONV) {              // last block: compaction scan
    __shared__ int s0[256], s1[256];
    int tid = threadIdx.x;
    int c0 = 0, c1 = 0;
#pragma unroll
    for (int j = 0; j < 16; ++j) {
      int v = tgt[tid * 16 + j];
      c0 += (v >= CUT0 && v < CUT1);
      c1 += (v >= CUT1);
    }
    s0[tid] = c0; s1[tid] = c1;
    __syncthreads();
    for (int off = 1; off < 256; off <<= 1) {
      int a0 = (tid >= off) ? s0[tid - off] : 0;
      int a1 = (tid >= off) ? s1[tid - off] : 0;
      __syncthreads();
      s0[tid] += a0; s1[tid] += a1;
      __syncthreads();
    }
    int b0 = s0[tid] - c0, b1 = s1[tid] - c1;
#pragma unroll
    for (int j = 0; j < 16; ++j) {
      int row = tid * 16 + j;
      int v = tgt[row];
      if (v >= CUT0 && v < CUT1)      { l0[b0] = row; pos[row] = b0; ++b0; }
      else if (v >= CUT1)             { l1[b1] = row; pos[row] = b1 | POS_C1; ++b1; }
      else                            { pos[row] = POS_NONE; }
    }
    if (tid == 255) { cnt[0] = s0[255]; cnt[1] = s1[255]; }
    return;
  }
  long long i = ((long long)blockIdx.x * 256 + threadIdx.x) * 8;
  if (i >= TOT) return;
  if (i < BH) {                           // hidden -> swizzled bf16 tiles
    int c = (int)(i >> 3);
    int row = c >> 7, k8 = c & 127;
    const float* hp = hidden + (size_t)row * D + k8 * 8;
    float4 f0 = *(const float4*)hp, f1 = *(const float4*)(hp + 4);
    bf16x8 o = pack8(f0, f1, 1.f);
    size_t tb = (size_t)(row >> 6) * 131072;
    int boff = (((row & 63) * 2048 + k8 * 16) ^ ((row & 7) << 4));
    *(bf16x8*)((char*)hbf + tb + boff) = o;
    return;
  }
  long long j = i - BH;
  if (j < B0) {                           // head weights -> frag-transposed
    int c = (int)(j >> 10), k = (int)(j & 1023);
    bf16x8 o;
    if (c < HM) {
      const float* sp = hw + (size_t)c * D + k;
      float4 f0 = *(const float4*)sp, f1 = *(const float4*)(sp + 4);
      o = pack8(f0, f1, LOG2E);
    } else {
      o = bf16x8{0, 0, 0, 0, 0, 0, 0, 0};
    }
    *(bf16x8*)(dhw + fragT(c, k)) = o;
    return;
  }
  if (j >= B2 && j < B3) {                // proj0 -> frag-transposed
    long long off = j - B2;
    int c = (int)(off >> 10), k = (int)(off & 1023);
    const float* sp = p0 + off;
    float4 f0 = *(const float4*)sp, f1 = *(const float4*)(sp + 4);
    *(bf16x8*)(dp0 + fragT(c, k)) = pack8(f0, f1, 1.f);
    return;
  }
  if (j >= B3) {                          // proj1 -> frag-transposed
    long long off = j - B3;
    int c = (int)(off >> 10), k = (int)(off & 1023);
    const float* sp = p1 + off;
    float4 f0 = *(const float4*)sp, f1 = *(const float4*)(sp + 4);
    *(bf16x8*)(dp1 + fragT(c, k)) = pack8(f0, f1, 1.f);
    return;
  }
  // tail weights (linear, gload_lds-staged later)
  const float* src; unsigned short* dst; long long off, nsrc;
  if (j < B1) { src = t0; dst = dt0; off = j - B0; nsrc = (long long)T0M * 256; }
  else        { src = t1; dst = dt1; off = j - B1; nsrc = (long long)T1M * 64; }
  bf16x8 o;
  if (off < nsrc) {
    float4 f0 = *(const float4*)(src + off), f1 = *(const float4*)(src + off + 4);
    o = pack8(f0, f1, LOG2E);
  } else {
    o = bf16x8{0, 0, 0, 0, 0, 0, 0, 0};
  }
  *(bf16x8*)(dst + off) = o;
}

// ------ headz: head LSE GEMM + fused z-projection, coalesced frag-B -------

__global__ __launch_bounds__(512) void headz_k(const unsigned short* __restrict__ hbf,
    const unsigned short* __restrict__ hwbf, const unsigned short* __restrict__ p0bf,
    const unsigned short* __restrict__ p1bf, const int* __restrict__ posc,
    unsigned short* __restrict__ z0, unsigned short* __restrict__ z1,
    float* __restrict__ hs_part) {
  __shared__ char Ab[64 * 2048];            // 128 KB swizzled bf16 (pre-baked)
  __shared__ float red[8][64];
  int rb = blockIdx.x >> 2, slice = blockIdx.x & 3;
  int tid = threadIdx.x;

  const bf16x8* src = (const bf16x8*)(hbf + (size_t)rb * 65536);
  bf16x8* dstv = (bf16x8*)Ab;
#pragma unroll
  for (int j = 0; j < 16; ++j) dstv[j * 512 + tid] = src[j * 512 + tid];
  __syncthreads();

  int w = tid >> 6, l = tid & 63, lr = l & 15, kg = l >> 4;
  int tg0 = (slice * 8 + w) * 4;            // this wave's 4 head col-tiles
  int zt = slice * 8 + w;                   // this wave's z col-tile (if <20)
  bool hasz = zt < 20;
  const unsigned short* zb = hasz
      ? (zt < 16 ? p0bf + (size_t)zt * 16384 + l * 8
                 : p1bf + (size_t)(zt - 16) * 16384 + l * 8)
      : p0bf;
  f32x4 zero4 = {0.f, 0.f, 0.f, 0.f};
  f32x4 acc[4][4];                          // [rowgroup][tile]
  f32x4 zac[4];
#pragma unroll
  for (int rg = 0; rg < 4; ++rg) {
    zac[rg] = zero4;
#pragma unroll
    for (int t = 0; t < 4; ++t) acc[rg][t] = zero4;
  }

#pragma unroll 4
  for (int kc = 0; kc < 32; ++kc) {
    bf16x8 af[4], bf[4];
#pragma unroll
    for (int rg = 0; rg < 4; ++rg) {
      int addr = ((rg * 16 + lr) * 2048 + kc * 64 + kg * 16) ^ ((lr & 7) << 4);
      af[rg] = *(const bf16x8*)(Ab + addr);
    }
#pragma unroll
    for (int t = 0; t < 4; ++t)               // coalesced 1KB fragment loads
      bf[t] = *(const bf16x8*)(hwbf + ((size_t)(tg0 + t) * 32 + kc) * 512 + l * 8);
#pragma unroll
    for (int rg = 0; rg < 4; ++rg)
#pragma unroll
      for (int t = 0; t < 4; ++t)
        acc[rg][t] = __builtin_amdgcn_mfma_f32_16x16x32_bf16(af[rg], bf[t], acc[rg][t], 0, 0, 0);
    if (hasz) {                             // wave-uniform branch
      bf16x8 bz = *(const bf16x8*)(zb + (size_t)kc * 512);
#pragma unroll
      for (int rg = 0; rg < 4; ++rg)
        zac[rg] = __builtin_amdgcn_mfma_f32_16x16x32_bf16(af[rg], bz, zac[rg], 0, 0, 0);
    }
  }

  // head epilogue: sum exp2 over this wave's 64 cols
  float sv[4][4];
#pragma unroll
  for (int rg = 0; rg < 4; ++rg)
#pragma unroll
    for (int v = 0; v < 4; ++v) {
      float s = 0.f;
#pragma unroll
      for (int t = 0; t < 4; ++t) s += __builtin_amdgcn_exp2f(acc[rg][t][v]);
      sv[rg][v] = s;
    }
#pragma unroll
  for (int off = 1; off < 16; off <<= 1)
#pragma unroll
    for (int rg = 0; rg < 4; ++rg)
#pragma unroll
      for (int v = 0; v < 4; ++v) sv[rg][v] += __shfl_xor(sv[rg][v], off);
  if (lr == 0)
#pragma unroll
    for (int rg = 0; rg < 4; ++rg)
#pragma unroll
      for (int v = 0; v < 4; ++v) red[w][rg * 16 + kg * 4 + v] = sv[rg][v];

  // z epilogue: write compacted z rows (cluster-matched only)
  if (hasz) {
#pragma unroll
    for (int rg = 0; rg < 4; ++rg)
#pragma unroll
      for (int v = 0; v < 4; ++v) {
        int grow = rb * 64 + rg * 16 + kg * 4 + v;
        int pcv = posc[grow];
        if (zt < 16) {
          if (pcv < POS_C1)
            z0[(size_t)pcv * 256 + zt * 16 + lr] = f2bf(zac[rg][v]);
        } else {
          if (pcv != POS_NONE && pcv >= POS_C1)
            z1[(size_t)(pcv & (POS_C1 - 1)) * 64 + (zt - 16) * 16 + lr] = f2bf(zac[rg][v]);
        }
      }
  }
  __syncthreads();
  if (tid < 64) {
    float s = 0.f;
#pragma unroll
    for (int ww = 0; ww < 8; ++ww) s += red[ww][tid];
    hs_part[slice * N_ROWS + rb * 64 + tid] = s;
  }
}

// --- tails: row-split waves, B staged once per block in LDS (dbuf) --------

__device__ __forceinline__ void tail1_body(int bid, const unsigned short* __restrict__ z,
    const unsigned short* __restrict__ twbf, const int* __restrict__ list,
    const int* __restrict__ cntp, float* __restrict__ ts_part,
    char* __restrict__ Bl) {
  constexpr int MT = T1MP / 16;             // 2517
  constexpr int ST = (MT + SL1 - 1) / SL1;  // 27
  int n = *cntp;
  int rowblock = bid / SL1, slice = bid % SL1;
  int rowbase = rowblock * RPB1;
  if (rowbase >= n) return;                 // block-uniform
  int t0 = slice * ST, t1e = min(t0 + ST, MT);
  if (t0 >= t1e) return;                    // block-uniform
  int tid = threadIdx.x, w = tid >> 6, l = tid & 63, lr = l & 15, kg = l >> 4;

  bf16x8 a[2][2];
#pragma unroll
  for (int rg = 0; rg < 2; ++rg) {
    int idx = min(rowbase + w * 32 + rg * 16 + lr, n - 1);
    const unsigned short* zp = z + (size_t)idx * 64 + kg * 8;
    a[rg][0] = *(const bf16x8*)(zp);
    a[rg][1] = *(const bf16x8*)(zp + 32);
  }

  int sb = tid * 16;
  int stile = sb >> 11, scol = (sb >> 7) & 15;
  int sbyte = (sb & 127) ^ ((scol & 7) << 4);
  const char* tb = (const char*)twbf;
  int mtm1 = MT - 1;
  auto stage = [&](int gt, int buf) {
    int tA = min(gt + stile, mtm1);
    GLOAD_LDS16(tb + (size_t)tA * 2048 + scol * 128 + sbyte, Bl + buf * 4096 + sb);
  };

  int NG = (t1e - t0 + 1) >> 1;
  stage(t0, 0);
  __syncthreads();

  float s[2][4] = {};
  f32x4 zero4 = {0.f, 0.f, 0.f, 0.f};
  int rd0 = (lr * 128 + kg * 16) ^ ((lr & 7) << 4);
  int cur = 0;
  for (int g = 0; g < NG; ++g) {
    int gt = t0 + g * 2;
    if (g + 1 < NG) stage(gt + 2, cur ^ 1);
#pragma unroll
    for (int t = 0; t < 2; ++t) {
      if (gt + t < t1e) {                   // block-uniform guard
        const char* bb = Bl + cur * 4096 + t * 2048;
        bf16x8 b0 = *(const bf16x8*)(bb + rd0);
        bf16x8 b1 = *(const bf16x8*)(bb + (rd0 ^ 64));
        f32x4 acc0 = __builtin_amdgcn_mfma_f32_16x16x32_bf16(a[0][0], b0, zero4, 0, 0, 0);
        f32x4 acc1 = __builtin_amdgcn_mfma_f32_16x16x32_bf16(a[1][0], b0, zero4, 0, 0, 0);
        acc0 = __builtin_amdgcn_mfma_f32_16x16x32_bf16(a[0][1], b1, acc0, 0, 0, 0);
        acc1 = __builtin_amdgcn_mfma_f32_16x16x32_bf16(a[1][1], b1, acc1, 0, 0, 0);
#pragma unroll
        for (int v = 0; v < 4; ++v) {
          s[0][v] += __builtin_amdgcn_exp2f(acc0[v]);
          s[1][v] += __builtin_amdgcn_exp2f(acc1[v]);
        }
      }
    }
    __syncthreads();
    cur ^= 1;
  }

#pragma unroll
  for (int off = 1; off < 16; off <<= 1)
#pragma unroll
    for (int rg = 0; rg < 2; ++rg)
#pragma unroll
      for (int v = 0; v < 4; ++v) s[rg][v] += __shfl_xor(s[rg][v], off);
  if (lr == 0) {
#pragma unroll
    for (int rg = 0; rg < 2; ++rg)
#pragma unroll
      for (int v = 0; v < 4; ++v) {
        int idx = rowbase + w * 32 + rg * 16 + kg * 4 + v;
        if (idx < n)
          ts_part[(size_t)slice * N_ROWS + list[idx]] = s[rg][v];
      }
  }
}

__device__ __forceinline__ void tail0_body(int bid, const unsigned short* __restrict__ z,
    const unsigned short* __restrict__ twbf, const int* __restrict__ list,
    const int* __restrict__ cntp, float* __restrict__ ts_part,
    char* __restrict__ Bl) {
  constexpr int MT = T0MP / 16;             // 500
  constexpr int ST = (MT + SL0 - 1) / SL0;  // 8
  int n = *cntp;
  int rowblock = bid / SL0, slice = bid % SL0;
  int rowbase = rowblock * RPB0;
  if (rowbase >= n) return;
  int t0 = slice * ST, t1e = min(t0 + ST, MT);
  if (t0 >= t1e) return;
  int tid = threadIdx.x, w = tid >> 6, l = tid & 63, lr = l & 15, kg = l >> 4;

  bf16x8 a[8];
  {
    int idx = min(rowbase + w * 16 + lr, n - 1);
    const unsigned short* zp = z + (size_t)idx * 256 + kg * 8;
#pragma unroll
    for (int kc = 0; kc < 8; ++kc) a[kc] = *(const bf16x8*)(zp + kc * 32);
  }

  int sb0 = tid * 16, sb1 = sb0 + 4096;
  int c0s = sb0 >> 9, b0s = (sb0 & 511) ^ ((c0s & 7) << 4);
  int c1s = sb1 >> 9, b1s = (sb1 & 511) ^ ((c1s & 7) << 4);
  const char* tb = (const char*)twbf;
  auto stage = [&](int gt, int buf) {
    GLOAD_LDS16(tb + (size_t)gt * 8192 + c0s * 512 + b0s, Bl + buf * 8192 + sb0);
    GLOAD_LDS16(tb + (size_t)gt * 8192 + c1s * 512 + b1s, Bl + buf * 8192 + sb1);
  };

  int NG = t1e - t0;
  stage(t0, 0);
  __syncthreads();

  float s[4] = {};
  f32x4 zero4 = {0.f, 0.f, 0.f, 0.f};
  int swz = (lr & 7) << 4;
  int rdb = lr * 512 + kg * 16;
  int cur = 0;
  for (int g = 0; g < NG; ++g) {
    if (g + 1 < NG) stage(t0 + g + 1, cur ^ 1);
    const char* bb = Bl + cur * 8192;
    f32x4 acc = zero4;
#pragma unroll
    for (int kc = 0; kc < 8; ++kc) {
      bf16x8 b = *(const bf16x8*)(bb + ((rdb + kc * 64) ^ swz));
      acc = __builtin_amdgcn_mfma_f32_16x16x32_bf16(a[kc], b, acc, 0, 0, 0);
    }
#pragma unroll
    for (int v = 0; v < 4; ++v) s[v] += __builtin_amdgcn_exp2f(acc[v]);
    __syncthreads();
    cur ^= 1;
  }

#pragma unroll
  for (int off = 1; off < 16; off <<= 1)
#pragma unroll
    for (int v = 0; v < 4; ++v) s[v] += __shfl_xor(s[v], off);
  if (lr == 0) {
#pragma unroll
    for (int v = 0; v < 4; ++v) {
      int idx = rowbase + w * 16 + kg * 4 + v;
      if (idx < n)
        ts_part[(size_t)slice * N_ROWS + list[idx]] = s[v];
    }
  }
}

__global__ __launch_bounds__(256, 8) void tf_k(
    const unsigned short* __restrict__ z0, const unsigned short* __restrict__ t0bf,
    const unsigned short* __restrict__ z1, const unsigned short* __restrict__ t1bf,
    const int* __restrict__ l0, const int* __restrict__ l1,
    const int* __restrict__ cnt, float* __restrict__ ts0_part,
    float* __restrict__ ts1_part) {
  __shared__ char Bl[16384];
  int b = blockIdx.x;
  if (b < G_T1)
    tail1_body(b, z1, t1bf, l1, cnt + 1, ts1_part, Bl);
  else
    tail0_body(b - G_T1, z0, t0bf, l0, cnt + 0, ts0_part, Bl);
}

// ---------------- finalize ----------------

__global__ __launch_bounds__(256) void finalize_k(const float* __restrict__ hidden,
    const int* __restrict__ tgt, const float* __restrict__ head_w,
    const float* __restrict__ tail0, const float* __restrict__ tail1,
    const unsigned short* __restrict__ z0, const unsigned short* __restrict__ z1,
    const int* __restrict__ pos, const float* __restrict__ hs_part,
    const float* __restrict__ ts0_part, const float* __restrict__ ts1_part,
    float* __restrict__ out) {
  int w = threadIdx.x >> 6, l = threadIdx.x & 63;
  int row = blockIdx.x * 4 + w;
  int t = tgt[row];
  int jt = t < 0 ? 0 : (t < CUT0 ? t : (t < CUT1 ? CUT0 : CUT0 + 1));
  const float4* h4 = (const float4*)(hidden + (size_t)row * D);
  const float4* w4 = (const float4*)(head_w + (size_t)jt * D);
  float acc = 0.f;
#pragma unroll
  for (int j = 0; j < 4; ++j) {
    float4 a = h4[l + 64 * j], b = w4[l + 64 * j];
    acc += a.x * b.x + a.y * b.y + a.z * b.z + a.w * b.w;
  }
  float hp = (l < 4) ? hs_part[l * N_ROWS + row] : 0.f;
#pragma unroll
  for (int off = 32; off; off >>= 1) {
    acc += __shfl_xor(acc, off);
    hp  += __shfl_xor(hp, off);
  }
  float val = acc - __logf(hp - 46.f);      // subtract 46 zero-pad cols
  if (t >= CUT0) {
    int p = pos[row] & (POS_C1 - 1);
    float ta = 0.f, tp = 0.f;
    if (t < CUT1) {
      const unsigned short* zr = z0 + (size_t)p * 256;
      const float* tw = tail0 + (size_t)(t - CUT0) * 256;
#pragma unroll
      for (int j = 0; j < 4; ++j) ta += bf2f(zr[l + 64 * j]) * tw[l + 64 * j];
      tp = ts0_part[(size_t)l * N_ROWS + row];            // SL0 = 64 slices
    } else {
      const unsigned short* zr = z1 + (size_t)p * 64;
      const float* tw = tail1 + (size_t)(t - CUT1) * 64;
      ta = bf2f(zr[l]) * tw[l];
      tp = ts1_part[(size_t)l * N_ROWS + row];            // slices 0..63
      if (l < SL1 - 64) tp += ts1_part[(size_t)(64 + l) * N_ROWS + row];
    }
#pragma unroll
    for (int off = 32; off; off >>= 1) {
      ta += __shfl_xor(ta, off);
      tp += __shfl_xor(tp, off);
    }
    float lt = tp - ((t >= CUT1) ? 15.f : 0.f);  // subtract zero-pad cols
    val += ta - __logf(lt);
  }
  if (l == 0) out[row] = (t < 0) ? 0.f : val;
}

// ---------------- loss ----------------

__global__ __launch_bounds__(256) void loss_k(const float* __restrict__ out,
                                              const int* __restrict__ target,
                                              float* __restrict__ loss) {
  __shared__ float ssum[256];
  __shared__ int scnt[256];
  float s = 0.f; int c = 0;
  for (int i = threadIdx.x; i < N_ROWS; i += 256) {
    s += out[i];
    if (target[i] >= 0) c++;
  }
  ssum[threadIdx.x] = s; scnt[threadIdx.x] = c;
  __syncthreads();
  for (int off = 128; off; off >>= 1) {
    if (threadIdx.x < off) {
      ssum[threadIdx.x] += ssum[threadIdx.x + off];
      scnt[threadIdx.x] += scnt[threadIdx.x + off];
    }
    __syncthreads();
  }
  if (threadIdx.x == 0) {
    int nv = scnt[0];
    loss[0] = (nv > 0) ? (-ssum[0] / (float)nv) : 0.f;
  }
}

// ---------------- launch ----------------

extern "C" void kernel_launch(void* const* d_in, const int* in_sizes, int n_in,
                              void* d_out, int out_size, void* d_ws, size_t ws_size,
                              hipStream_t stream) {
  const float* hidden = (const float*)d_in[0];
  const int*   target = (const int*)d_in[1];
  const float* head_w = (const float*)d_in[2];
  const float* proj0  = (const float*)d_in[3];
  const float* tail0  = (const float*)d_in[4];
  const float* proj1  = (const float*)d_in[5];
  const float* tail1  = (const float*)d_in[6];
  float* out = (float*)d_out;

  char* wp = (char*)d_ws;
  auto alloc = [&](size_t bytes) {
    char* p = wp;
    wp += (bytes + 255) & ~(size_t)255;
    return p;
  };
  int* cnt   = (int*)alloc(8);
  int* list0 = (int*)alloc(N_ROWS * 4);
  int* list1 = (int*)alloc(N_ROWS * 4);
  int* pos   = (int*)alloc(N_ROWS * 4);
  unsigned short* hbf  = (unsigned short*)alloc((size_t)N_ROWS * D * 2);
  unsigned short* hwbf = (unsigned short*)alloc((size_t)HMP * D * 2);
  unsigned short* t0bf = (unsigned short*)alloc((size_t)T0MP * 256 * 2);
  unsigned short* t1bf = (unsigned short*)alloc((size_t)T1MP * 64 * 2);
  unsigned short* p0bf = (unsigned short*)alloc((size_t)256 * D * 2);
  unsigned short* p1bf = (unsigned short*)alloc((size_t)64 * D * 2);
  unsigned short* z0   = (unsigned short*)alloc((size_t)N_ROWS * 256 * 2);
  unsigned short* z1   = (unsigned short*)alloc((size_t)N_ROWS * 64 * 2);
  float* hs_part  = (float*)alloc((size_t)4 * N_ROWS * 4);
  float* ts0_part = (float*)alloc((size_t)SL0 * N_ROWS * 4);
  float* ts1_part = (float*)alloc((size_t)SL1 * N_ROWS * 4);

  prep_k<<<NCONV + 1, 256, 0, stream>>>(hidden, head_w, tail0, tail1, proj0, proj1,
                                        hbf, hwbf, t0bf, t1bf, p0bf, p1bf,
                                        target, cnt, list0, list1, pos);
  headz_k<<<(N_ROWS / 64) * 4, 512, 0, stream>>>(hbf, hwbf, p0bf, p1bf, pos,
                                                 z0, z1, hs_part);
  tf_k<<<G_T1 + G_T0, 256, 0, stream>>>(z0, t0bf, z1, t1bf, list0, list1, cnt,
                                        ts0_part, ts1_part);
  finalize_k<<<N_ROWS / 4, 256, 0, stream>>>(hidden, target, head_w, tail0, tail1,
                                             z0, z1, pos, hs_part, ts0_part, ts1_part, out);
  loss_k<<<1, 256, 0, stream>>>(out, target, out + N_ROWS);
}